// Round 10
// baseline (652.837 us; speedup 1.0000x reference)
//
#include <hip/hip_runtime.h>

// GRU-D: nf=64, B=128, T=100, I=64, H=128, C=256.
// R10 = R9 structure with BB=16, grid=512, 2 blocks/CU (launch_bounds(512,4)).
//       wz/wh/wg resident (72 VGPR); r-weights streamed from L2 per step.
#define NF 64
#define BATCH 128
#define TT 100
#define II 64
#define HH 128
#define CC 256
#define BB 16
#define NTHR 512
#define PSTRIDE 111297

#define OFF_ZW 0
#define OFF_ZB 32768
#define OFF_RW 32896
#define OFF_RB 65664
#define OFF_HW 65792
#define OFF_HB 98560
#define OFF_GXW 98688
#define OFF_GXB 102784
#define OFF_GHW 102848
#define OFF_GHB 111040
#define OFF_FCW 111168
#define OFF_FCB 111296

// ws layout (bf16 elems), per-lane MFMA B-fragment order (hi only)
#define ZR_PER_N 65536
#define H_BASE   (64 * ZR_PER_N)
#define H_PER_N  32768
#define G_BASE   (H_BASE + 64 * H_PER_N)
#define G_PER_N  8192
#define WS_ELEMS (G_BASE + 64 * G_PER_N)   // 6815744 bf16 = 13 MB

typedef __bf16 bf16x8 __attribute__((ext_vector_type(8)));
typedef __bf16 bf16x2 __attribute__((ext_vector_type(2)));
typedef float f32x4 __attribute__((ext_vector_type(4)));
typedef float f32x2 __attribute__((ext_vector_type(2)));

__device__ __forceinline__ f32x4 mfma16(bf16x8 a, bf16x8 b, f32x4 c) {
  return __builtin_amdgcn_mfma_f32_16x16x32_bf16(a, b, c, 0, 0, 0);
}
__device__ __forceinline__ float rcpf_(float x) { return __builtin_amdgcn_rcpf(x); }
__device__ __forceinline__ float sigmoidf_(float x) { return rcpf_(1.f + __expf(-x)); }
__device__ __forceinline__ float tanhf_(float x) {
  float e = __expf(-2.f * __builtin_fabsf(x));
  float t = (1.f - e) * rcpf_(1.f + e);
  return x < 0.f ? -t : t;
}
// row swizzle within a [64][8] plane: physical row = r ^ 2*((r>>4)&3)
__device__ __forceinline__ int SW(int x) { return x ^ (((x >> 4) & 3) << 1); }

// LDS pool element-offsets (plane = [64 rows][8 j] = 512 elems):
#define XA(par, kt)   (((par)*2 + (kt)) * 512)        // x hi      [0,2048)
#define MAPL(par, kt) (2048 + XA(par, kt))            // mask      [2048,4096)
#define DAH(kt)       (4096 + (kt)*512)               // d hi      [4096,5120)
#define HAH(q)        (5120 + (q)*512)                // h hi      [5120,7168)
#define HAL(q)        (7168 + (q)*512)                // h lo      [7168,9216)
#define RHH(q)        (9216 + (q)*512)                // r*h hi    [9216,11264)
#define RHL(q)        (11264 + (q)*512)               // r*h lo    [11264,13312)
#define POOL_ELEMS 13312

// ---- repack: params -> B-fragment-ordered bf16 (hi only) in ws ----
__global__ void repack_kernel(const float* __restrict__ p, __bf16* __restrict__ ws) {
  const int total = 4194304 + 2097152 + 524288;
  for (int e = blockIdx.x * 256 + threadIdx.x; e < total; e += gridDim.x * 256) {
    float wv; int dst;
    if (e < 4194304) {  // ZR
      int j = e & 7, l = (e >> 3) & 63, nt = (e >> 9) & 15, kt = (e >> 13) & 7, n = e >> 16;
      int c = kt * 32 + (l >> 4) * 8 + j, l15 = l & 15;
      long pn = (long)n * PSTRIDE;
      wv = (nt < 8) ? p[pn + OFF_ZW + (nt * 16 + l15) * CC + c]
                    : p[pn + OFF_RW + ((nt - 8) * 16 + l15) * CC + c];
      dst = n * ZR_PER_N + (kt * 16 + nt) * 512 + l * 8 + j;
    } else if (e < 4194304 + 2097152) {  // H
      int e2 = e - 4194304;
      int j = e2 & 7, l = (e2 >> 3) & 63, nt = (e2 >> 9) & 7, kt = (e2 >> 12) & 7, n = e2 >> 15;
      int c = kt * 32 + (l >> 4) * 8 + j, l15 = l & 15;
      wv = p[(long)n * PSTRIDE + OFF_HW + (nt * 16 + l15) * CC + c];
      dst = H_BASE + n * H_PER_N + (kt * 8 + nt) * 512 + l * 8 + j;
    } else {  // G
      int e2 = e - (4194304 + 2097152);
      int j = e2 & 7, l = (e2 >> 3) & 63, nt = (e2 >> 9) & 7, kt = (e2 >> 12) & 1, n = e2 >> 13;
      int c = kt * 32 + (l >> 4) * 8 + j, l15 = l & 15;
      wv = p[(long)n * PSTRIDE + OFF_GHW + (nt * 16 + l15) * II + c];
      dst = G_BASE + n * G_PER_N + (kt * 8 + nt) * 512 + l * 8 + j;
    }
    ws[dst] = (__bf16)wv;
  }
}

// One block per (n, 16-batch chunk); 8 waves; 2 blocks/CU.
__global__ __launch_bounds__(NTHR, 4) void grud_main(
    const float* __restrict__ p, const float* __restrict__ X,
    const float* __restrict__ XL, const float* __restrict__ XM,
    const float* __restrict__ MK, const float* __restrict__ DE,
    const __bf16* __restrict__ ws, float* __restrict__ out) {
  __shared__ __align__(16) __bf16 pool[POOL_ELEMS];

  const int tid = threadIdx.x;
  const int w = tid >> 6, l = tid & 63;
  const int l15 = l & 15, lg = l >> 4;
  const int n = blockIdx.x & 63;            // same-n blocks -> same XCD
  const int b0 = (blockIdx.x >> 6) * BB;
  const long pn = (long)n * PSTRIDE;
  const int cw = w * 16 + l15;
  const int sl = SW(l);

  const __bf16* __restrict__ wzr_base = ws + n * ZR_PER_N;

  // ---- resident weights: z (32) + h (32) + g (8) VGPR; r streamed ----
  bf16x8 wzR[8], whR[8], wgR[2];
  {
    const __bf16* wh_ = ws + H_BASE + n * H_PER_N;
    const __bf16* wg_ = ws + G_BASE + n * G_PER_N;
#pragma unroll
    for (int kt = 0; kt < 8; ++kt) {
      wzR[kt] = *(const bf16x8*)(wzr_base + (kt * 16 + w) * 512 + l * 8);
      whR[kt] = *(const bf16x8*)(wh_ + (kt * 8 + w) * 512 + l * 8);
    }
#pragma unroll
    for (int kt = 0; kt < 2; ++kt)
      wgR[kt] = *(const bf16x8*)(wg_ + (kt * 8 + w) * 512 + l * 8);
  }

  const float zb = p[pn + OFF_ZB + cw];
  const float rb = p[pn + OFF_RB + cw];
  const float hb = p[pn + OFF_HB + cw];
  const float gb = p[pn + OFF_GHB + cw];

  // this lane's h-column coords (global k = 64 + cw)
  const int hq = ((64 + cw) >> 5) - 2;                 // plane q 0..3
  const int qh = (cw >> 3) & 3;
  const int hj = cw & 7;
  int hsrow[4];
#pragma unroll
  for (int r = 0; r < 4; ++r) hsrow[r] = qh * 16 + ((lg * 4 + r) ^ (qh << 1));

  // phase-A mapping: thread -> (batch row 0..15, 2-wide i block)
  const int arow = tid >> 5;
  const int ai0 = (tid & 31) * 2;
  const int akt = ai0 >> 5;
  const int salane = SW(((ai0 >> 3) & 3) * 16 + arow);
  const int aj = ai0 & 7;
  const float* __restrict__ Xp  = X  + (long)(b0 + arow) * TT * II + ai0;
  const float* __restrict__ XLp = XL + (long)(b0 + arow) * TT * II + ai0;
  const float* __restrict__ MKp = MK + ((long)(n * BATCH + b0 + arow) * TT) * II + ai0;
  const float* __restrict__ DEp = DE + ((long)(n * BATCH + b0 + arow) * TT) * II + ai0;
  const float gxd0 = p[pn + OFF_GXW + ai0 * 65];
  const float gxd1 = p[pn + OFF_GXW + (ai0 + 1) * 65];
  const float gxb0 = p[pn + OFF_GXB + ai0];
  const float gxb1 = p[pn + OFF_GXB + ai0 + 1];

  float h[4] = {0.f, 0.f, 0.f, 0.f};

  // ---- prologue: zero hA planes; A(0); prefetch(1) ----
  for (int e = tid; e < 4096; e += NTHR) pool[5120 + e] = (__bf16)0.f;

  f32x2 fx  = *(const f32x2*)Xp;
  f32x2 fxl = *(const f32x2*)XLp;
  f32x2 fxm = *(const f32x2*)(XM + ai0);
  f32x2 fm  = __builtin_nontemporal_load((const f32x2*)MKp);
  f32x2 fd  = __builtin_nontemporal_load((const f32x2*)DEp);
  {
    float m0 = fm[0], m1 = fm[1], d0 = fd[0], d1 = fd[1];
    float dx0 = __expf(-fmaxf(fmaf(d0, gxd0, gxb0), 0.f));
    float dx1 = __expf(-fmaxf(fmaf(d1, gxd1, gxb1), 0.f));
    float xv0 = m0 * fx[0] + (1.f - m0) * (dx0 * fxl[0] + (1.f - dx0) * fxm[0]);
    float xv1 = m1 * fx[1] + (1.f - m1) * (dx1 * fxl[1] + (1.f - dx1) * fxm[1]);
    *(bf16x2*)&pool[XA(0, akt) + salane * 8 + aj] = bf16x2{(__bf16)xv0, (__bf16)xv1};
    *(bf16x2*)&pool[MAPL(0, akt) + salane * 8 + aj] = bf16x2{(__bf16)m0, (__bf16)m1};
  }
  {
    const long to = (long)(TT > 1 ? 1 : 0) * II;
    fx  = *(const f32x2*)(Xp + to);
    fxl = *(const f32x2*)(XLp + to);
    fxm = *(const f32x2*)(XM + to + ai0);
    fm  = __builtin_nontemporal_load((const f32x2*)(MKp + to));
    fd  = __builtin_nontemporal_load((const f32x2*)(DEp + to));
  }
  __syncthreads();

  for (int t = 0; t < TT; ++t) {
    const int par = t & 1, parn = par ^ 1;
    const bool more = (t + 1 < TT);

    // ================= C-region =================
    // laundered r-weight base: force in-loop L2 loads (demand stays < cap)
    int zoff = 0;
    asm volatile("" : "+v"(zoff));
    const __bf16* wr_t = wzr_base + zoff;

    // A(t+1): elementwise from prefetched regs -> parn planes + dA
    if (more) {
      float m0 = fm[0], m1 = fm[1], d0 = fd[0], d1 = fd[1];
      float dx0 = __expf(-fmaxf(fmaf(d0, gxd0, gxb0), 0.f));
      float dx1 = __expf(-fmaxf(fmaf(d1, gxd1, gxb1), 0.f));
      float xv0 = m0 * fx[0] + (1.f - m0) * (dx0 * fxl[0] + (1.f - dx0) * fxm[0]);
      float xv1 = m1 * fx[1] + (1.f - m1) * (dx1 * fxl[1] + (1.f - dx1) * fxm[1]);
      *(bf16x2*)&pool[XA(parn, akt) + salane * 8 + aj] = bf16x2{(__bf16)xv0, (__bf16)xv1};
      *(bf16x2*)&pool[MAPL(parn, akt) + salane * 8 + aj] = bf16x2{(__bf16)m0, (__bf16)m1};
      *(bf16x2*)&pool[DAH(akt) + salane * 8 + aj] = bf16x2{(__bf16)d0, (__bf16)d1};
      // prefetch t+2
      const long to = (long)(t + 2 < TT ? t + 2 : TT - 1) * II;
      fx  = *(const f32x2*)(Xp + to);
      fxl = *(const f32x2*)(XLp + to);
      fxm = *(const f32x2*)(XM + to + ai0);
      fm  = __builtin_nontemporal_load((const f32x2*)(MKp + to));
      fd  = __builtin_nontemporal_load((const f32x2*)(DEp + to));
    }

    // z,r MFMA over comb(par); r-weights loaded per kt (live range ~1)
    float zv[4];
    {
      f32x4 az = {0.f, 0.f, 0.f, 0.f}, ar = {0.f, 0.f, 0.f, 0.f};
#pragma unroll
      for (int kt = 0; kt < 8; ++kt) {
        bf16x8 br = *(const bf16x8*)(wr_t + (kt * 16 + 8 + w) * 512 + l * 8);
        const __bf16* ahp = (kt < 2) ? &pool[XA(par, kt) + sl * 8]
                          : (kt < 6) ? &pool[HAH(kt - 2) + sl * 8]
                                     : &pool[MAPL(par, kt - 6) + sl * 8];
        bf16x8 ah = *(const bf16x8*)ahp;
        az = mfma16(ah, wzR[kt], az);
        ar = mfma16(ah, br, ar);
        if (kt >= 2 && kt < 6) {  // h-region lo term
          bf16x8 al = *(const bf16x8*)&pool[HAL(kt - 2) + sl * 8];
          az = mfma16(al, wzR[kt], az);
          ar = mfma16(al, br, ar);
        }
      }
#pragma unroll
      for (int r = 0; r < 4; ++r) {
        zv[r] = sigmoidf_(az[r] + zb);
        float rv = sigmoidf_(ar[r] + rb);
        float rh = rv * h[r];
        __bf16 v = (__bf16)rh;
        pool[RHH(hq) + hsrow[r] * 8 + hj] = v;
        pool[RHL(hq) + hsrow[r] * 8 + hj] = (__bf16)(rh - (float)v);
      }
    }
    __syncthreads();  // bar1

    // ================= D-region =================
    {
      f32x4 ahh = {0.f, 0.f, 0.f, 0.f};
#pragma unroll
      for (int kt = 0; kt < 8; ++kt) {
        const __bf16* ahp = (kt < 2) ? &pool[XA(par, kt) + sl * 8]
                          : (kt < 6) ? &pool[RHH(kt - 2) + sl * 8]
                                     : &pool[MAPL(par, kt - 6) + sl * 8];
        bf16x8 ah = *(const bf16x8*)ahp;
        ahh = mfma16(ah, whR[kt], ahh);
        if (kt >= 2 && kt < 6) {
          bf16x8 al = *(const bf16x8*)&pool[RHL(kt - 2) + sl * 8];
          ahh = mfma16(al, whR[kt], ahh);
        }
      }
      // delta_h(t+1) matmul (h-independent)
      f32x4 ad = {0.f, 0.f, 0.f, 0.f};
      if (more) {
#pragma unroll
        for (int kt = 0; kt < 2; ++kt) {
          bf16x8 ah = *(const bf16x8*)&pool[DAH(kt) + sl * 8];
          ad = mfma16(ah, wgR[kt], ad);
        }
      }
#pragma unroll
      for (int r = 0; r < 4; ++r) {
        float ht = tanhf_(ahh[r] + hb);
        float hn = (1.f - zv[r]) * h[r] + zv[r] * ht;
        if (more) {
          hn *= __expf(-fmaxf(ad[r] + gb, 0.f));   // decay for step t+1
          __bf16 v = (__bf16)hn;
          pool[HAH(hq) + hsrow[r] * 8 + hj] = v;
          pool[HAL(hq) + hsrow[r] * 8 + hj] = (__bf16)(hn - (float)v);
        }
        h[r] = hn;
      }
    }
    __syncthreads();  // bar2
  }

  // ---- fc epilogue (overlays pool) ----
  float* hst = (float*)pool;                 // [16][132]
#pragma unroll
  for (int r = 0; r < 4; ++r) hst[(lg * 4 + r) * 132 + cw] = h[r];
  __syncthreads();
  if (tid < BB) {
    float acc = p[pn + OFF_FCB];
    for (int j = 0; j < HH; ++j) acc = fmaf(hst[tid * 132 + j], p[pn + OFF_FCW + j], acc);
    out[n * BATCH + b0 + tid] = sigmoidf_(acc);
  }
}

extern "C" void kernel_launch(void* const* d_in, const int* in_sizes, int n_in,
                              void* d_out, int out_size, void* d_ws, size_t ws_size,
                              hipStream_t stream) {
  const float* p  = (const float*)d_in[0];
  const float* X  = (const float*)d_in[1];
  const float* XL = (const float*)d_in[2];
  const float* XM = (const float*)d_in[3];
  const float* MK = (const float*)d_in[4];
  const float* DE = (const float*)d_in[5];
  float* out = (float*)d_out;
  __bf16* ws = (__bf16*)d_ws;
  if (ws_size < (size_t)WS_ELEMS * 2) return;

  hipLaunchKernelGGL(repack_kernel, dim3(4096), dim3(256), 0, stream, p, ws);
  hipLaunchKernelGGL(grud_main, dim3(NF * (BATCH / BB)), dim3(NTHR), 0, stream,
                     p, X, XL, XM, MK, DE, ws, out);
}

// Round 11
// 376.751 us; speedup vs baseline: 1.7328x; 1.7328x over previous
//
#include <hip/hip_runtime.h>

// GRU-D: nf=64, B=128, T=100, I=64, H=128, C=256.
// R11 = R9 structure at BB=16, grid=512. All weights resident (104 VGPR),
//       launch_bounds(512,2) -> compiler ~112 VGPR -> HW fits 2 blocks/CU
//       (4 waves/SIMD) from resource limits alone. No streaming, no launder.
#define NF 64
#define BATCH 128
#define TT 100
#define II 64
#define HH 128
#define CC 256
#define BB 16
#define NTHR 512
#define PSTRIDE 111297

#define OFF_ZW 0
#define OFF_ZB 32768
#define OFF_RW 32896
#define OFF_RB 65664
#define OFF_HW 65792
#define OFF_HB 98560
#define OFF_GXW 98688
#define OFF_GXB 102784
#define OFF_GHW 102848
#define OFF_GHB 111040
#define OFF_FCW 111168
#define OFF_FCB 111296

// ws layout (bf16 elems), per-lane MFMA B-fragment order (hi only)
#define ZR_PER_N 65536
#define H_BASE   (64 * ZR_PER_N)
#define H_PER_N  32768
#define G_BASE   (H_BASE + 64 * H_PER_N)
#define G_PER_N  8192
#define WS_ELEMS (G_BASE + 64 * G_PER_N)   // 6815744 bf16 = 13 MB

typedef __bf16 bf16x8 __attribute__((ext_vector_type(8)));
typedef __bf16 bf16x2 __attribute__((ext_vector_type(2)));
typedef float f32x4 __attribute__((ext_vector_type(4)));
typedef float f32x2 __attribute__((ext_vector_type(2)));

__device__ __forceinline__ f32x4 mfma16(bf16x8 a, bf16x8 b, f32x4 c) {
  return __builtin_amdgcn_mfma_f32_16x16x32_bf16(a, b, c, 0, 0, 0);
}
__device__ __forceinline__ float rcpf_(float x) { return __builtin_amdgcn_rcpf(x); }
__device__ __forceinline__ float sigmoidf_(float x) { return rcpf_(1.f + __expf(-x)); }
__device__ __forceinline__ float tanhf_(float x) {
  float e = __expf(-2.f * __builtin_fabsf(x));
  float t = (1.f - e) * rcpf_(1.f + e);
  return x < 0.f ? -t : t;
}
// row swizzle within a [64][8] plane: physical row = r ^ 2*((r>>4)&3)
__device__ __forceinline__ int SW(int x) { return x ^ (((x >> 4) & 3) << 1); }

// LDS pool element-offsets (plane = [64 rows][8 j] = 512 elems):
#define XA(par, kt)   (((par)*2 + (kt)) * 512)        // x hi      [0,2048)
#define MAPL(par, kt) (2048 + XA(par, kt))            // mask      [2048,4096)
#define DAH(kt)       (4096 + (kt)*512)               // d hi      [4096,5120)
#define HAH(q)        (5120 + (q)*512)                // h hi      [5120,7168)
#define HAL(q)        (7168 + (q)*512)                // h lo      [7168,9216)
#define RHH(q)        (9216 + (q)*512)                // r*h hi    [9216,11264)
#define RHL(q)        (11264 + (q)*512)               // r*h lo    [11264,13312)
#define POOL_ELEMS 13312

// ---- repack: params -> B-fragment-ordered bf16 (hi only) in ws ----
__global__ void repack_kernel(const float* __restrict__ p, __bf16* __restrict__ ws) {
  const int total = 4194304 + 2097152 + 524288;
  for (int e = blockIdx.x * 256 + threadIdx.x; e < total; e += gridDim.x * 256) {
    float wv; int dst;
    if (e < 4194304) {  // ZR
      int j = e & 7, l = (e >> 3) & 63, nt = (e >> 9) & 15, kt = (e >> 13) & 7, n = e >> 16;
      int c = kt * 32 + (l >> 4) * 8 + j, l15 = l & 15;
      long pn = (long)n * PSTRIDE;
      wv = (nt < 8) ? p[pn + OFF_ZW + (nt * 16 + l15) * CC + c]
                    : p[pn + OFF_RW + ((nt - 8) * 16 + l15) * CC + c];
      dst = n * ZR_PER_N + (kt * 16 + nt) * 512 + l * 8 + j;
    } else if (e < 4194304 + 2097152) {  // H
      int e2 = e - 4194304;
      int j = e2 & 7, l = (e2 >> 3) & 63, nt = (e2 >> 9) & 7, kt = (e2 >> 12) & 7, n = e2 >> 15;
      int c = kt * 32 + (l >> 4) * 8 + j, l15 = l & 15;
      wv = p[(long)n * PSTRIDE + OFF_HW + (nt * 16 + l15) * CC + c];
      dst = H_BASE + n * H_PER_N + (kt * 8 + nt) * 512 + l * 8 + j;
    } else {  // G
      int e2 = e - (4194304 + 2097152);
      int j = e2 & 7, l = (e2 >> 3) & 63, nt = (e2 >> 9) & 7, kt = (e2 >> 12) & 1, n = e2 >> 13;
      int c = kt * 32 + (l >> 4) * 8 + j, l15 = l & 15;
      wv = p[(long)n * PSTRIDE + OFF_GHW + (nt * 16 + l15) * II + c];
      dst = G_BASE + n * G_PER_N + (kt * 8 + nt) * 512 + l * 8 + j;
    }
    ws[dst] = (__bf16)wv;
  }
}

// One block per (n, 16-batch chunk); 8 waves; 2 blocks/CU via resource fit.
__global__ __launch_bounds__(NTHR, 2) void grud_main(
    const float* __restrict__ p, const float* __restrict__ X,
    const float* __restrict__ XL, const float* __restrict__ XM,
    const float* __restrict__ MK, const float* __restrict__ DE,
    const __bf16* __restrict__ ws, float* __restrict__ out) {
  __shared__ __align__(16) __bf16 pool[POOL_ELEMS];

  const int tid = threadIdx.x;
  const int w = tid >> 6, l = tid & 63;
  const int l15 = l & 15, lg = l >> 4;
  const int n = blockIdx.x & 63;            // same-n blocks -> same XCD
  const int b0 = (blockIdx.x >> 6) * BB;
  const long pn = (long)n * PSTRIDE;
  const int cw = w * 16 + l15;
  const int sl = SW(l);

  // ---- ALL weight fragments resident (104 VGPR, loaded once) ----
  bf16x8 wzR[8], wrR[8], whR[8], wgR[2];
  {
    const __bf16* wzr = ws + n * ZR_PER_N;
    const __bf16* wh_ = ws + H_BASE + n * H_PER_N;
    const __bf16* wg_ = ws + G_BASE + n * G_PER_N;
#pragma unroll
    for (int kt = 0; kt < 8; ++kt) {
      wzR[kt] = *(const bf16x8*)(wzr + (kt * 16 + w) * 512 + l * 8);
      wrR[kt] = *(const bf16x8*)(wzr + (kt * 16 + 8 + w) * 512 + l * 8);
      whR[kt] = *(const bf16x8*)(wh_ + (kt * 8 + w) * 512 + l * 8);
    }
#pragma unroll
    for (int kt = 0; kt < 2; ++kt)
      wgR[kt] = *(const bf16x8*)(wg_ + (kt * 8 + w) * 512 + l * 8);
  }

  const float zb = p[pn + OFF_ZB + cw];
  const float rb = p[pn + OFF_RB + cw];
  const float hb = p[pn + OFF_HB + cw];
  const float gb = p[pn + OFF_GHB + cw];

  // this lane's h-column coords (global k = 64 + cw)
  const int hq = ((64 + cw) >> 5) - 2;                 // plane q 0..3
  const int qh = (cw >> 3) & 3;
  const int hj = cw & 7;
  int hsrow[4];
#pragma unroll
  for (int r = 0; r < 4; ++r) hsrow[r] = qh * 16 + ((lg * 4 + r) ^ (qh << 1));

  // phase-A mapping: thread -> (batch row 0..15, 2-wide i block)
  const int arow = tid >> 5;
  const int ai0 = (tid & 31) * 2;
  const int akt = ai0 >> 5;
  const int salane = SW(((ai0 >> 3) & 3) * 16 + arow);
  const int aj = ai0 & 7;
  const float* __restrict__ Xp  = X  + (long)(b0 + arow) * TT * II + ai0;
  const float* __restrict__ XLp = XL + (long)(b0 + arow) * TT * II + ai0;
  const float* __restrict__ MKp = MK + ((long)(n * BATCH + b0 + arow) * TT) * II + ai0;
  const float* __restrict__ DEp = DE + ((long)(n * BATCH + b0 + arow) * TT) * II + ai0;
  const float gxd0 = p[pn + OFF_GXW + ai0 * 65];
  const float gxd1 = p[pn + OFF_GXW + (ai0 + 1) * 65];
  const float gxb0 = p[pn + OFF_GXB + ai0];
  const float gxb1 = p[pn + OFF_GXB + ai0 + 1];

  float h[4] = {0.f, 0.f, 0.f, 0.f};

  // ---- prologue: zero hA planes; A(0); prefetch(1) ----
  for (int e = tid; e < 4096; e += NTHR) pool[5120 + e] = (__bf16)0.f;

  f32x2 fx  = *(const f32x2*)Xp;
  f32x2 fxl = *(const f32x2*)XLp;
  f32x2 fxm = *(const f32x2*)(XM + ai0);
  f32x2 fm  = __builtin_nontemporal_load((const f32x2*)MKp);
  f32x2 fd  = __builtin_nontemporal_load((const f32x2*)DEp);
  {
    float m0 = fm[0], m1 = fm[1], d0 = fd[0], d1 = fd[1];
    float dx0 = __expf(-fmaxf(fmaf(d0, gxd0, gxb0), 0.f));
    float dx1 = __expf(-fmaxf(fmaf(d1, gxd1, gxb1), 0.f));
    float xv0 = m0 * fx[0] + (1.f - m0) * (dx0 * fxl[0] + (1.f - dx0) * fxm[0]);
    float xv1 = m1 * fx[1] + (1.f - m1) * (dx1 * fxl[1] + (1.f - dx1) * fxm[1]);
    *(bf16x2*)&pool[XA(0, akt) + salane * 8 + aj] = bf16x2{(__bf16)xv0, (__bf16)xv1};
    *(bf16x2*)&pool[MAPL(0, akt) + salane * 8 + aj] = bf16x2{(__bf16)m0, (__bf16)m1};
  }
  {
    const long to = (long)(TT > 1 ? 1 : 0) * II;
    fx  = *(const f32x2*)(Xp + to);
    fxl = *(const f32x2*)(XLp + to);
    fxm = *(const f32x2*)(XM + to + ai0);
    fm  = __builtin_nontemporal_load((const f32x2*)(MKp + to));
    fd  = __builtin_nontemporal_load((const f32x2*)(DEp + to));
  }
  __syncthreads();

  for (int t = 0; t < TT; ++t) {
    const int par = t & 1, parn = par ^ 1;
    const bool more = (t + 1 < TT);

    // ================= C-region =================
    // A(t+1): elementwise from prefetched regs -> parn planes + dA
    if (more) {
      float m0 = fm[0], m1 = fm[1], d0 = fd[0], d1 = fd[1];
      float dx0 = __expf(-fmaxf(fmaf(d0, gxd0, gxb0), 0.f));
      float dx1 = __expf(-fmaxf(fmaf(d1, gxd1, gxb1), 0.f));
      float xv0 = m0 * fx[0] + (1.f - m0) * (dx0 * fxl[0] + (1.f - dx0) * fxm[0]);
      float xv1 = m1 * fx[1] + (1.f - m1) * (dx1 * fxl[1] + (1.f - dx1) * fxm[1]);
      *(bf16x2*)&pool[XA(parn, akt) + salane * 8 + aj] = bf16x2{(__bf16)xv0, (__bf16)xv1};
      *(bf16x2*)&pool[MAPL(parn, akt) + salane * 8 + aj] = bf16x2{(__bf16)m0, (__bf16)m1};
      *(bf16x2*)&pool[DAH(akt) + salane * 8 + aj] = bf16x2{(__bf16)d0, (__bf16)d1};
      // prefetch t+2
      const long to = (long)(t + 2 < TT ? t + 2 : TT - 1) * II;
      fx  = *(const f32x2*)(Xp + to);
      fxl = *(const f32x2*)(XLp + to);
      fxm = *(const f32x2*)(XM + to + ai0);
      fm  = __builtin_nontemporal_load((const f32x2*)(MKp + to));
      fd  = __builtin_nontemporal_load((const f32x2*)(DEp + to));
    }

    // z,r MFMA over comb(par)
    float zv[4];
    {
      f32x4 az = {0.f, 0.f, 0.f, 0.f}, ar = {0.f, 0.f, 0.f, 0.f};
#pragma unroll
      for (int kt = 0; kt < 8; ++kt) {
        const __bf16* ahp = (kt < 2) ? &pool[XA(par, kt) + sl * 8]
                          : (kt < 6) ? &pool[HAH(kt - 2) + sl * 8]
                                     : &pool[MAPL(par, kt - 6) + sl * 8];
        bf16x8 ah = *(const bf16x8*)ahp;
        az = mfma16(ah, wzR[kt], az);
        ar = mfma16(ah, wrR[kt], ar);
        if (kt >= 2 && kt < 6) {  // h-region lo term
          bf16x8 al = *(const bf16x8*)&pool[HAL(kt - 2) + sl * 8];
          az = mfma16(al, wzR[kt], az);
          ar = mfma16(al, wrR[kt], ar);
        }
      }
#pragma unroll
      for (int r = 0; r < 4; ++r) {
        zv[r] = sigmoidf_(az[r] + zb);
        float rv = sigmoidf_(ar[r] + rb);
        float rh = rv * h[r];
        __bf16 v = (__bf16)rh;
        pool[RHH(hq) + hsrow[r] * 8 + hj] = v;
        pool[RHL(hq) + hsrow[r] * 8 + hj] = (__bf16)(rh - (float)v);
      }
    }
    __syncthreads();  // bar1

    // ================= D-region =================
    {
      f32x4 ahh = {0.f, 0.f, 0.f, 0.f};
#pragma unroll
      for (int kt = 0; kt < 8; ++kt) {
        const __bf16* ahp = (kt < 2) ? &pool[XA(par, kt) + sl * 8]
                          : (kt < 6) ? &pool[RHH(kt - 2) + sl * 8]
                                     : &pool[MAPL(par, kt - 6) + sl * 8];
        bf16x8 ah = *(const bf16x8*)ahp;
        ahh = mfma16(ah, whR[kt], ahh);
        if (kt >= 2 && kt < 6) {
          bf16x8 al = *(const bf16x8*)&pool[RHL(kt - 2) + sl * 8];
          ahh = mfma16(al, whR[kt], ahh);
        }
      }
      // delta_h(t+1) matmul (h-independent)
      f32x4 ad = {0.f, 0.f, 0.f, 0.f};
      if (more) {
#pragma unroll
        for (int kt = 0; kt < 2; ++kt) {
          bf16x8 ah = *(const bf16x8*)&pool[DAH(kt) + sl * 8];
          ad = mfma16(ah, wgR[kt], ad);
        }
      }
#pragma unroll
      for (int r = 0; r < 4; ++r) {
        float ht = tanhf_(ahh[r] + hb);
        float hn = (1.f - zv[r]) * h[r] + zv[r] * ht;
        if (more) {
          hn *= __expf(-fmaxf(ad[r] + gb, 0.f));   // decay for step t+1
          __bf16 v = (__bf16)hn;
          pool[HAH(hq) + hsrow[r] * 8 + hj] = v;
          pool[HAL(hq) + hsrow[r] * 8 + hj] = (__bf16)(hn - (float)v);
        }
        h[r] = hn;
      }
    }
    __syncthreads();  // bar2
  }

  // ---- fc epilogue (overlays pool) ----
  float* hst = (float*)pool;                 // [16][132]
#pragma unroll
  for (int r = 0; r < 4; ++r) hst[(lg * 4 + r) * 132 + cw] = h[r];
  __syncthreads();
  if (tid < BB) {
    float acc = p[pn + OFF_FCB];
    for (int j = 0; j < HH; ++j) acc = fmaf(hst[tid * 132 + j], p[pn + OFF_FCW + j], acc);
    out[n * BATCH + b0 + tid] = sigmoidf_(acc);
  }
}

extern "C" void kernel_launch(void* const* d_in, const int* in_sizes, int n_in,
                              void* d_out, int out_size, void* d_ws, size_t ws_size,
                              hipStream_t stream) {
  const float* p  = (const float*)d_in[0];
  const float* X  = (const float*)d_in[1];
  const float* XL = (const float*)d_in[2];
  const float* XM = (const float*)d_in[3];
  const float* MK = (const float*)d_in[4];
  const float* DE = (const float*)d_in[5];
  float* out = (float*)d_out;
  __bf16* ws = (__bf16*)d_ws;
  if (ws_size < (size_t)WS_ELEMS * 2) return;

  hipLaunchKernelGGL(repack_kernel, dim3(4096), dim3(256), 0, stream, p, ws);
  hipLaunchKernelGGL(grud_main, dim3(NF * (BATCH / BB)), dim3(NTHR), 0, stream,
                     p, X, XL, XM, MK, DE, ws, out);
}

// Round 12
// 254.358 us; speedup vs baseline: 2.5666x; 1.4812x over previous
//
#include <hip/hip_runtime.h>

// GRU-D: nf=64, B=128, T=100, I=64, H=128, C=256.
// R12 = R9 (BB=32, all weights resident, 2 barriers/step) with ALL LDS
//       activations single-bf16 (h-lo and rh-lo planes dropped; h state
//       itself stays exact f32 in registers). 52 MFMA/wave/step.
#define NF 64
#define BATCH 128
#define TT 100
#define II 64
#define HH 128
#define CC 256
#define BB 32
#define NTHR 512
#define PSTRIDE 111297

#define OFF_ZW 0
#define OFF_ZB 32768
#define OFF_RW 32896
#define OFF_RB 65664
#define OFF_HW 65792
#define OFF_HB 98560
#define OFF_GXW 98688
#define OFF_GXB 102784
#define OFF_GHW 102848
#define OFF_GHB 111040
#define OFF_FCW 111168
#define OFF_FCB 111296

// ws layout (bf16 elems), per-lane MFMA B-fragment order (hi only)
#define ZR_PER_N 65536
#define H_BASE   (64 * ZR_PER_N)
#define H_PER_N  32768
#define G_BASE   (H_BASE + 64 * H_PER_N)
#define G_PER_N  8192
#define WS_ELEMS (G_BASE + 64 * G_PER_N)   // 6815744 bf16 = 13 MB

typedef __bf16 bf16x8 __attribute__((ext_vector_type(8)));
typedef __bf16 bf16x4 __attribute__((ext_vector_type(4)));
typedef float f32x4 __attribute__((ext_vector_type(4)));

__device__ __forceinline__ f32x4 mfma16(bf16x8 a, bf16x8 b, f32x4 c) {
  return __builtin_amdgcn_mfma_f32_16x16x32_bf16(a, b, c, 0, 0, 0);
}
__device__ __forceinline__ float rcpf_(float x) { return __builtin_amdgcn_rcpf(x); }
__device__ __forceinline__ float sigmoidf_(float x) { return rcpf_(1.f + __expf(-x)); }
__device__ __forceinline__ float tanhf_(float x) {
  float e = __expf(-2.f * __builtin_fabsf(x));
  float t = (1.f - e) * rcpf_(1.f + e);
  return x < 0.f ? -t : t;
}
// row swizzle within a [64][8] plane: physical row = r ^ 2*((r>>4)&3)
__device__ __forceinline__ int SW(int x) { return x ^ (((x >> 4) & 3) << 1); }

// LDS pool element-offsets (plane = [64 rows][8 j] = 512 elems):
//  XA(par,mt,kt)   x hi   [0, 4096)
//  MAPL(par,mt,kt) mask   [4096, 8192)
//  DAH(mt,kt)      d hi   [8192, 10240)
//  HAH(mt,q)       h hi   [10240, 14336)
//  RHH(mt,q)       r*h hi [14336, 18432)
#define XA(par, mt, kt)  ((((par)*2 + (mt)) * 2 + (kt)) * 512)
#define MAPL(par, mt, kt) (4096 + XA(par, mt, kt))
#define DAH(mt, kt) (8192 + (((mt)*2 + (kt)) * 512))
#define HAH(mt, q) (10240 + (((mt)*4 + (q)) * 512))
#define RHH(mt, q) (14336 + (((mt)*4 + (q)) * 512))
#define POOL_ELEMS 18432

// ---- repack: params -> B-fragment-ordered bf16 (hi only) in ws ----
__global__ void repack_kernel(const float* __restrict__ p, __bf16* __restrict__ ws) {
  const int total = 4194304 + 2097152 + 524288;
  for (int e = blockIdx.x * 256 + threadIdx.x; e < total; e += gridDim.x * 256) {
    float wv; int dst;
    if (e < 4194304) {  // ZR
      int j = e & 7, l = (e >> 3) & 63, nt = (e >> 9) & 15, kt = (e >> 13) & 7, n = e >> 16;
      int c = kt * 32 + (l >> 4) * 8 + j, l15 = l & 15;
      long pn = (long)n * PSTRIDE;
      wv = (nt < 8) ? p[pn + OFF_ZW + (nt * 16 + l15) * CC + c]
                    : p[pn + OFF_RW + ((nt - 8) * 16 + l15) * CC + c];
      dst = n * ZR_PER_N + (kt * 16 + nt) * 512 + l * 8 + j;
    } else if (e < 4194304 + 2097152) {  // H
      int e2 = e - 4194304;
      int j = e2 & 7, l = (e2 >> 3) & 63, nt = (e2 >> 9) & 7, kt = (e2 >> 12) & 7, n = e2 >> 15;
      int c = kt * 32 + (l >> 4) * 8 + j, l15 = l & 15;
      wv = p[(long)n * PSTRIDE + OFF_HW + (nt * 16 + l15) * CC + c];
      dst = H_BASE + n * H_PER_N + (kt * 8 + nt) * 512 + l * 8 + j;
    } else {  // G
      int e2 = e - (4194304 + 2097152);
      int j = e2 & 7, l = (e2 >> 3) & 63, nt = (e2 >> 9) & 7, kt = (e2 >> 12) & 1, n = e2 >> 13;
      int c = kt * 32 + (l >> 4) * 8 + j, l15 = l & 15;
      wv = p[(long)n * PSTRIDE + OFF_GHW + (nt * 16 + l15) * II + c];
      dst = G_BASE + n * G_PER_N + (kt * 8 + nt) * 512 + l * 8 + j;
    }
    ws[dst] = (__bf16)wv;
  }
}

// One block per (n, 32-batch chunk); 8 waves; 1 block/CU.
__global__ __launch_bounds__(NTHR, 2) void grud_main(
    const float* __restrict__ p, const float* __restrict__ X,
    const float* __restrict__ XL, const float* __restrict__ XM,
    const float* __restrict__ MK, const float* __restrict__ DE,
    const __bf16* __restrict__ ws, float* __restrict__ out) {
  __shared__ __align__(16) __bf16 pool[POOL_ELEMS];

  const int tid = threadIdx.x;
  const int w = tid >> 6, l = tid & 63;
  const int l15 = l & 15, lg = l >> 4;
  const int n = blockIdx.x & 63;            // same-n blocks -> same XCD
  const int b0 = (blockIdx.x >> 6) * BB;
  const long pn = (long)n * PSTRIDE;
  const int cw = w * 16 + l15;
  const int sl = SW(l);

  // ---- all weight fragments in registers (loaded once, 104 VGPR) ----
  bf16x8 wgR[2], wzR[8], wrR[8], whR[8];
  {
    const __bf16* wzr = ws + n * ZR_PER_N;
    const __bf16* wh_ = ws + H_BASE + n * H_PER_N;
    const __bf16* wg_ = ws + G_BASE + n * G_PER_N;
#pragma unroll
    for (int kt = 0; kt < 2; ++kt)
      wgR[kt] = *(const bf16x8*)(wg_ + (kt * 8 + w) * 512 + l * 8);
#pragma unroll
    for (int kt = 0; kt < 8; ++kt) {
      wzR[kt] = *(const bf16x8*)(wzr + (kt * 16 + w) * 512 + l * 8);
      wrR[kt] = *(const bf16x8*)(wzr + (kt * 16 + 8 + w) * 512 + l * 8);
      whR[kt] = *(const bf16x8*)(wh_ + (kt * 8 + w) * 512 + l * 8);
    }
  }

  const float zb = p[pn + OFF_ZB + cw];
  const float rb = p[pn + OFF_RB + cw];
  const float hb = p[pn + OFF_HB + cw];
  const float gb = p[pn + OFF_GHB + cw];

  // this lane's h-column coords (global k = 64 + cw)
  const int hq = ((64 + cw) >> 5) - 2;                 // plane q 0..3
  const int qh = (cw >> 3) & 3;
  const int hj = cw & 7;
  int hsrow[4];
#pragma unroll
  for (int r = 0; r < 4; ++r) hsrow[r] = qh * 16 + ((lg * 4 + r) ^ (qh << 1));

  // phase-A mapping: thread -> (batch row 0..31, 4-wide i block)
  const int arow = tid >> 4;
  const int ai0 = (tid & 15) * 4;
  const int amt = arow >> 4;
  const int akt = ai0 >> 5;
  const int salane = SW(((ai0 >> 3) & 3) * 16 + (arow & 15));
  const int aj = ai0 & 7;
  const float* __restrict__ Xp  = X  + (long)(b0 + arow) * TT * II + ai0;
  const float* __restrict__ XLp = XL + (long)(b0 + arow) * TT * II + ai0;
  const float* __restrict__ MKp = MK + ((long)(n * BATCH + b0 + arow) * TT) * II + ai0;
  const float* __restrict__ DEp = DE + ((long)(n * BATCH + b0 + arow) * TT) * II + ai0;
  float gxd4[4], gxb4[4];
#pragma unroll
  for (int u = 0; u < 4; ++u) {
    gxd4[u] = p[pn + OFF_GXW + (ai0 + u) * 65];
    gxb4[u] = p[pn + OFF_GXB + ai0 + u];
  }

  float h[2][4] = {{0.f, 0.f, 0.f, 0.f}, {0.f, 0.f, 0.f, 0.f}};

  // ---- prologue: zero hA planes; A(0); prefetch(1) ----
  for (int e = tid; e < 4096; e += NTHR) pool[10240 + e] = (__bf16)0.f;

  f32x4 fx  = *(const f32x4*)Xp;
  f32x4 fxl = *(const f32x4*)XLp;
  f32x4 fxm = *(const f32x4*)(XM + ai0);
  f32x4 fm  = __builtin_nontemporal_load((const f32x4*)MKp);
  f32x4 fd  = __builtin_nontemporal_load((const f32x4*)DEp);
  {
    bf16x4 xh, mh;
#pragma unroll
    for (int u = 0; u < 4; ++u) {
      float m = fm[u], d = fd[u];
      float dx = __expf(-fmaxf(fmaf(d, gxd4[u], gxb4[u]), 0.f));
      float xv = m * fx[u] + (1.f - m) * (dx * fxl[u] + (1.f - dx) * fxm[u]);
      xh[u] = (__bf16)xv;
      mh[u] = (__bf16)m;
    }
    *(bf16x4*)&pool[XA(0, amt, akt) + salane * 8 + aj] = xh;
    *(bf16x4*)&pool[MAPL(0, amt, akt) + salane * 8 + aj] = mh;
  }
  {
    const long to = (long)(TT > 1 ? 1 : 0) * II;
    fx  = *(const f32x4*)(Xp + to);
    fxl = *(const f32x4*)(XLp + to);
    fxm = *(const f32x4*)(XM + to + ai0);
    fm  = __builtin_nontemporal_load((const f32x4*)(MKp + to));
    fd  = __builtin_nontemporal_load((const f32x4*)(DEp + to));
  }
  __syncthreads();

  for (int t = 0; t < TT; ++t) {
    const int par = t & 1, parn = par ^ 1;
    const bool more = (t + 1 < TT);

    // ================= C-region =================
    // A(t+1): elementwise from prefetched regs -> parn planes + dA
    if (more) {
      bf16x4 xh, mh, dh;
#pragma unroll
      for (int u = 0; u < 4; ++u) {
        float m = fm[u], d = fd[u];
        float dx = __expf(-fmaxf(fmaf(d, gxd4[u], gxb4[u]), 0.f));
        float xv = m * fx[u] + (1.f - m) * (dx * fxl[u] + (1.f - dx) * fxm[u]);
        xh[u] = (__bf16)xv;
        mh[u] = (__bf16)m;
        dh[u] = (__bf16)d;
      }
      *(bf16x4*)&pool[XA(parn, amt, akt) + salane * 8 + aj] = xh;
      *(bf16x4*)&pool[MAPL(parn, amt, akt) + salane * 8 + aj] = mh;
      *(bf16x4*)&pool[DAH(amt, akt) + salane * 8 + aj] = dh;
      // prefetch t+2
      const long to = (long)(t + 2 < TT ? t + 2 : TT - 1) * II;
      fx  = *(const f32x4*)(Xp + to);
      fxl = *(const f32x4*)(XLp + to);
      fxm = *(const f32x4*)(XM + to + ai0);
      fm  = __builtin_nontemporal_load((const f32x4*)(MKp + to));
      fd  = __builtin_nontemporal_load((const f32x4*)(DEp + to));
    }

    // z,r MFMA over comb(par) — single-bf16 activations
    float zv[2][4];
#pragma unroll
    for (int mt = 0; mt < 2; ++mt) {
      f32x4 az = {0.f, 0.f, 0.f, 0.f}, ar = {0.f, 0.f, 0.f, 0.f};
#pragma unroll
      for (int kt = 0; kt < 8; ++kt) {
        const __bf16* ahp = (kt < 2) ? &pool[XA(par, mt, kt) + sl * 8]
                          : (kt < 6) ? &pool[HAH(mt, kt - 2) + sl * 8]
                                     : &pool[MAPL(par, mt, kt - 6) + sl * 8];
        bf16x8 ah = *(const bf16x8*)ahp;
        az = mfma16(ah, wzR[kt], az);
        ar = mfma16(ah, wrR[kt], ar);
      }
#pragma unroll
      for (int r = 0; r < 4; ++r) {
        zv[mt][r] = sigmoidf_(az[r] + zb);
        float rv = sigmoidf_(ar[r] + rb);
        float rh = rv * h[mt][r];
        pool[RHH(mt, hq) + hsrow[r] * 8 + hj] = (__bf16)rh;
      }
    }
    __syncthreads();  // bar1

    // ================= D-region =================
#pragma unroll
    for (int mt = 0; mt < 2; ++mt) {
      f32x4 ahh = {0.f, 0.f, 0.f, 0.f};
#pragma unroll
      for (int kt = 0; kt < 8; ++kt) {
        const __bf16* ahp = (kt < 2) ? &pool[XA(par, mt, kt) + sl * 8]
                          : (kt < 6) ? &pool[RHH(mt, kt - 2) + sl * 8]
                                     : &pool[MAPL(par, mt, kt - 6) + sl * 8];
        bf16x8 ah = *(const bf16x8*)ahp;
        ahh = mfma16(ah, whR[kt], ahh);
      }
      // delta_h(t+1) matmul (h-independent)
      f32x4 ad = {0.f, 0.f, 0.f, 0.f};
      if (more) {
#pragma unroll
        for (int kt = 0; kt < 2; ++kt) {
          bf16x8 ah = *(const bf16x8*)&pool[DAH(mt, kt) + sl * 8];
          ad = mfma16(ah, wgR[kt], ad);
        }
      }
#pragma unroll
      for (int r = 0; r < 4; ++r) {
        float ht = tanhf_(ahh[r] + hb);
        float hn = (1.f - zv[mt][r]) * h[mt][r] + zv[mt][r] * ht;
        if (more) {
          hn *= __expf(-fmaxf(ad[r] + gb, 0.f));   // decay for step t+1
          pool[HAH(mt, hq) + hsrow[r] * 8 + hj] = (__bf16)hn;
        }
        h[mt][r] = hn;
      }
    }
    __syncthreads();  // bar2
  }

  // ---- fc epilogue (overlays pool) ----
  float* hst = (float*)pool;                 // [32][132]
#pragma unroll
  for (int mt = 0; mt < 2; ++mt)
#pragma unroll
    for (int r = 0; r < 4; ++r) hst[(mt * 16 + lg * 4 + r) * 132 + cw] = h[mt][r];
  __syncthreads();
  if (tid < BB) {
    float acc = p[pn + OFF_FCB];
    for (int j = 0; j < HH; ++j) acc = fmaf(hst[tid * 132 + j], p[pn + OFF_FCW + j], acc);
    out[n * BATCH + b0 + tid] = sigmoidf_(acc);
  }
}

extern "C" void kernel_launch(void* const* d_in, const int* in_sizes, int n_in,
                              void* d_out, int out_size, void* d_ws, size_t ws_size,
                              hipStream_t stream) {
  const float* p  = (const float*)d_in[0];
  const float* X  = (const float*)d_in[1];
  const float* XL = (const float*)d_in[2];
  const float* XM = (const float*)d_in[3];
  const float* MK = (const float*)d_in[4];
  const float* DE = (const float*)d_in[5];
  float* out = (float*)d_out;
  __bf16* ws = (__bf16*)d_ws;
  if (ws_size < (size_t)WS_ELEMS * 2) return;

  hipLaunchKernelGGL(repack_kernel, dim3(4096), dim3(256), 0, stream, p, ws);
  hipLaunchKernelGGL(grud_main, dim3(NF * (BATCH / BB)), dim3(NTHR), 0, stream,
                     p, X, XL, XM, MK, DE, ws, out);
}

// Round 13
// 247.266 us; speedup vs baseline: 2.6402x; 1.0287x over previous
//
#include <hip/hip_runtime.h>

// GRU-D: nf=64, B=128, T=100, I=64, H=128, C=256.
// R13 = R12 + VALU cuts: bias-preloaded MFMA accumulators, algebraic
//       refactor of the phase-A blend. Structure unchanged.
#define NF 64
#define BATCH 128
#define TT 100
#define II 64
#define HH 128
#define CC 256
#define BB 32
#define NTHR 512
#define PSTRIDE 111297

#define OFF_ZW 0
#define OFF_ZB 32768
#define OFF_RW 32896
#define OFF_RB 65664
#define OFF_HW 65792
#define OFF_HB 98560
#define OFF_GXW 98688
#define OFF_GXB 102784
#define OFF_GHW 102848
#define OFF_GHB 111040
#define OFF_FCW 111168
#define OFF_FCB 111296

// ws layout (bf16 elems), per-lane MFMA B-fragment order (hi only)
#define ZR_PER_N 65536
#define H_BASE   (64 * ZR_PER_N)
#define H_PER_N  32768
#define G_BASE   (H_BASE + 64 * H_PER_N)
#define G_PER_N  8192
#define WS_ELEMS (G_BASE + 64 * G_PER_N)   // 6815744 bf16 = 13 MB

typedef __bf16 bf16x8 __attribute__((ext_vector_type(8)));
typedef __bf16 bf16x4 __attribute__((ext_vector_type(4)));
typedef float f32x4 __attribute__((ext_vector_type(4)));

__device__ __forceinline__ f32x4 mfma16(bf16x8 a, bf16x8 b, f32x4 c) {
  return __builtin_amdgcn_mfma_f32_16x16x32_bf16(a, b, c, 0, 0, 0);
}
__device__ __forceinline__ float rcpf_(float x) { return __builtin_amdgcn_rcpf(x); }
__device__ __forceinline__ float sigmoidf_(float x) { return rcpf_(1.f + __expf(-x)); }
__device__ __forceinline__ float tanhf_(float x) {
  float e = __expf(-2.f * __builtin_fabsf(x));
  float t = (1.f - e) * rcpf_(1.f + e);
  return x < 0.f ? -t : t;
}
// row swizzle within a [64][8] plane: physical row = r ^ 2*((r>>4)&3)
__device__ __forceinline__ int SW(int x) { return x ^ (((x >> 4) & 3) << 1); }

// LDS pool element-offsets (plane = [64 rows][8 j] = 512 elems):
#define XA(par, mt, kt)  ((((par)*2 + (mt)) * 2 + (kt)) * 512)
#define MAPL(par, mt, kt) (4096 + XA(par, mt, kt))
#define DAH(mt, kt) (8192 + (((mt)*2 + (kt)) * 512))
#define HAH(mt, q) (10240 + (((mt)*4 + (q)) * 512))
#define RHH(mt, q) (14336 + (((mt)*4 + (q)) * 512))
#define POOL_ELEMS 18432

// ---- repack: params -> B-fragment-ordered bf16 (hi only) in ws ----
__global__ void repack_kernel(const float* __restrict__ p, __bf16* __restrict__ ws) {
  const int total = 4194304 + 2097152 + 524288;
  for (int e = blockIdx.x * 256 + threadIdx.x; e < total; e += gridDim.x * 256) {
    float wv; int dst;
    if (e < 4194304) {  // ZR
      int j = e & 7, l = (e >> 3) & 63, nt = (e >> 9) & 15, kt = (e >> 13) & 7, n = e >> 16;
      int c = kt * 32 + (l >> 4) * 8 + j, l15 = l & 15;
      long pn = (long)n * PSTRIDE;
      wv = (nt < 8) ? p[pn + OFF_ZW + (nt * 16 + l15) * CC + c]
                    : p[pn + OFF_RW + ((nt - 8) * 16 + l15) * CC + c];
      dst = n * ZR_PER_N + (kt * 16 + nt) * 512 + l * 8 + j;
    } else if (e < 4194304 + 2097152) {  // H
      int e2 = e - 4194304;
      int j = e2 & 7, l = (e2 >> 3) & 63, nt = (e2 >> 9) & 7, kt = (e2 >> 12) & 7, n = e2 >> 15;
      int c = kt * 32 + (l >> 4) * 8 + j, l15 = l & 15;
      wv = p[(long)n * PSTRIDE + OFF_HW + (nt * 16 + l15) * CC + c];
      dst = H_BASE + n * H_PER_N + (kt * 8 + nt) * 512 + l * 8 + j;
    } else {  // G
      int e2 = e - (4194304 + 2097152);
      int j = e2 & 7, l = (e2 >> 3) & 63, nt = (e2 >> 9) & 7, kt = (e2 >> 12) & 1, n = e2 >> 13;
      int c = kt * 32 + (l >> 4) * 8 + j, l15 = l & 15;
      wv = p[(long)n * PSTRIDE + OFF_GHW + (nt * 16 + l15) * II + c];
      dst = G_BASE + n * G_PER_N + (kt * 8 + nt) * 512 + l * 8 + j;
    }
    ws[dst] = (__bf16)wv;
  }
}

// One block per (n, 32-batch chunk); 8 waves; 1 block/CU.
__global__ __launch_bounds__(NTHR, 2) void grud_main(
    const float* __restrict__ p, const float* __restrict__ X,
    const float* __restrict__ XL, const float* __restrict__ XM,
    const float* __restrict__ MK, const float* __restrict__ DE,
    const __bf16* __restrict__ ws, float* __restrict__ out) {
  __shared__ __align__(16) __bf16 pool[POOL_ELEMS];

  const int tid = threadIdx.x;
  const int w = tid >> 6, l = tid & 63;
  const int l15 = l & 15, lg = l >> 4;
  const int n = blockIdx.x & 63;            // same-n blocks -> same XCD
  const int b0 = (blockIdx.x >> 6) * BB;
  const long pn = (long)n * PSTRIDE;
  const int cw = w * 16 + l15;
  const int sl = SW(l);

  // ---- all weight fragments in registers (loaded once, 104 VGPR) ----
  bf16x8 wgR[2], wzR[8], wrR[8], whR[8];
  {
    const __bf16* wzr = ws + n * ZR_PER_N;
    const __bf16* wh_ = ws + H_BASE + n * H_PER_N;
    const __bf16* wg_ = ws + G_BASE + n * G_PER_N;
#pragma unroll
    for (int kt = 0; kt < 2; ++kt)
      wgR[kt] = *(const bf16x8*)(wg_ + (kt * 8 + w) * 512 + l * 8);
#pragma unroll
    for (int kt = 0; kt < 8; ++kt) {
      wzR[kt] = *(const bf16x8*)(wzr + (kt * 16 + w) * 512 + l * 8);
      wrR[kt] = *(const bf16x8*)(wzr + (kt * 16 + 8 + w) * 512 + l * 8);
      whR[kt] = *(const bf16x8*)(wh_ + (kt * 8 + w) * 512 + l * 8);
    }
  }

  const float zb = p[pn + OFF_ZB + cw];
  const float rb = p[pn + OFF_RB + cw];
  const float hb = p[pn + OFF_HB + cw];
  const float gb = p[pn + OFF_GHB + cw];
  const f32x4 zb4 = {zb, zb, zb, zb};
  const f32x4 rb4 = {rb, rb, rb, rb};
  const f32x4 hb4 = {hb, hb, hb, hb};
  const f32x4 gb4 = {gb, gb, gb, gb};

  // this lane's h-column coords (global k = 64 + cw)
  const int hq = ((64 + cw) >> 5) - 2;                 // plane q 0..3
  const int qh = (cw >> 3) & 3;
  const int hj = cw & 7;
  int hsrow[4];
#pragma unroll
  for (int r = 0; r < 4; ++r) hsrow[r] = qh * 16 + ((lg * 4 + r) ^ (qh << 1));

  // phase-A mapping: thread -> (batch row 0..31, 4-wide i block)
  const int arow = tid >> 4;
  const int ai0 = (tid & 15) * 4;
  const int amt = arow >> 4;
  const int akt = ai0 >> 5;
  const int salane = SW(((ai0 >> 3) & 3) * 16 + (arow & 15));
  const int aj = ai0 & 7;
  const float* __restrict__ Xp  = X  + (long)(b0 + arow) * TT * II + ai0;
  const float* __restrict__ XLp = XL + (long)(b0 + arow) * TT * II + ai0;
  const float* __restrict__ MKp = MK + ((long)(n * BATCH + b0 + arow) * TT) * II + ai0;
  const float* __restrict__ DEp = DE + ((long)(n * BATCH + b0 + arow) * TT) * II + ai0;
  float gxd4[4], gxb4v[4];
#pragma unroll
  for (int u = 0; u < 4; ++u) {
    gxd4[u] = p[pn + OFF_GXW + (ai0 + u) * 65];
    gxb4v[u] = p[pn + OFF_GXB + ai0 + u];
  }

  float h[2][4] = {{0.f, 0.f, 0.f, 0.f}, {0.f, 0.f, 0.f, 0.f}};

  // ---- prologue: zero hA planes; A(0); prefetch(1) ----
  for (int e = tid; e < 4096; e += NTHR) pool[10240 + e] = (__bf16)0.f;

  f32x4 fx  = *(const f32x4*)Xp;
  f32x4 fxl = *(const f32x4*)XLp;
  f32x4 fxm = *(const f32x4*)(XM + ai0);
  f32x4 fm  = __builtin_nontemporal_load((const f32x4*)MKp);
  f32x4 fd  = __builtin_nontemporal_load((const f32x4*)DEp);
  {
    bf16x4 xh, mh;
#pragma unroll
    for (int u = 0; u < 4; ++u) {
      float m = fm[u], d = fd[u];
      float dx = __expf(-fmaxf(fmaf(d, gxd4[u], gxb4v[u]), 0.f));
      float b = fmaf(dx, fxl[u] - fxm[u], fxm[u]);
      float xv = fmaf(m, fx[u] - b, b);
      xh[u] = (__bf16)xv;
      mh[u] = (__bf16)m;
    }
    *(bf16x4*)&pool[XA(0, amt, akt) + salane * 8 + aj] = xh;
    *(bf16x4*)&pool[MAPL(0, amt, akt) + salane * 8 + aj] = mh;
  }
  {
    const long to = (long)(TT > 1 ? 1 : 0) * II;
    fx  = *(const f32x4*)(Xp + to);
    fxl = *(const f32x4*)(XLp + to);
    fxm = *(const f32x4*)(XM + to + ai0);
    fm  = __builtin_nontemporal_load((const f32x4*)(MKp + to));
    fd  = __builtin_nontemporal_load((const f32x4*)(DEp + to));
  }
  __syncthreads();

  for (int t = 0; t < TT; ++t) {
    const int par = t & 1, parn = par ^ 1;
    const bool more = (t + 1 < TT);

    // ================= C-region =================
    // A(t+1): elementwise from prefetched regs -> parn planes + dA
    if (more) {
      bf16x4 xh, mh, dh;
#pragma unroll
      for (int u = 0; u < 4; ++u) {
        float m = fm[u], d = fd[u];
        float dx = __expf(-fmaxf(fmaf(d, gxd4[u], gxb4v[u]), 0.f));
        float b = fmaf(dx, fxl[u] - fxm[u], fxm[u]);
        float xv = fmaf(m, fx[u] - b, b);
        xh[u] = (__bf16)xv;
        mh[u] = (__bf16)m;
        dh[u] = (__bf16)d;
      }
      *(bf16x4*)&pool[XA(parn, amt, akt) + salane * 8 + aj] = xh;
      *(bf16x4*)&pool[MAPL(parn, amt, akt) + salane * 8 + aj] = mh;
      *(bf16x4*)&pool[DAH(amt, akt) + salane * 8 + aj] = dh;
      // prefetch t+2
      const long to = (long)(t + 2 < TT ? t + 2 : TT - 1) * II;
      fx  = *(const f32x4*)(Xp + to);
      fxl = *(const f32x4*)(XLp + to);
      fxm = *(const f32x4*)(XM + to + ai0);
      fm  = __builtin_nontemporal_load((const f32x4*)(MKp + to));
      fd  = __builtin_nontemporal_load((const f32x4*)(DEp + to));
    }

    // z,r MFMA over comb(par) — accumulators pre-loaded with bias
    float zv[2][4];
#pragma unroll
    for (int mt = 0; mt < 2; ++mt) {
      f32x4 az = zb4, ar = rb4;
#pragma unroll
      for (int kt = 0; kt < 8; ++kt) {
        const __bf16* ahp = (kt < 2) ? &pool[XA(par, mt, kt) + sl * 8]
                          : (kt < 6) ? &pool[HAH(mt, kt - 2) + sl * 8]
                                     : &pool[MAPL(par, mt, kt - 6) + sl * 8];
        bf16x8 ah = *(const bf16x8*)ahp;
        az = mfma16(ah, wzR[kt], az);
        ar = mfma16(ah, wrR[kt], ar);
      }
#pragma unroll
      for (int r = 0; r < 4; ++r) {
        zv[mt][r] = sigmoidf_(az[r]);
        float rv = sigmoidf_(ar[r]);
        float rh = rv * h[mt][r];
        pool[RHH(mt, hq) + hsrow[r] * 8 + hj] = (__bf16)rh;
      }
    }
    __syncthreads();  // bar1

    // ================= D-region =================
#pragma unroll
    for (int mt = 0; mt < 2; ++mt) {
      f32x4 ahh = hb4;
#pragma unroll
      for (int kt = 0; kt < 8; ++kt) {
        const __bf16* ahp = (kt < 2) ? &pool[XA(par, mt, kt) + sl * 8]
                          : (kt < 6) ? &pool[RHH(mt, kt - 2) + sl * 8]
                                     : &pool[MAPL(par, mt, kt - 6) + sl * 8];
        bf16x8 ah = *(const bf16x8*)ahp;
        ahh = mfma16(ah, whR[kt], ahh);
      }
      // delta_h(t+1) matmul (h-independent), bias pre-loaded
      f32x4 ad = gb4;
      if (more) {
#pragma unroll
        for (int kt = 0; kt < 2; ++kt) {
          bf16x8 ah = *(const bf16x8*)&pool[DAH(mt, kt) + sl * 8];
          ad = mfma16(ah, wgR[kt], ad);
        }
      }
#pragma unroll
      for (int r = 0; r < 4; ++r) {
        float ht = tanhf_(ahh[r]);
        float hn = fmaf(zv[mt][r], ht - h[mt][r], h[mt][r]);
        if (more) {
          hn *= __expf(-fmaxf(ad[r], 0.f));        // decay for step t+1
          pool[HAH(mt, hq) + hsrow[r] * 8 + hj] = (__bf16)hn;
        }
        h[mt][r] = hn;
      }
    }
    __syncthreads();  // bar2
  }

  // ---- fc epilogue (overlays pool) ----
  float* hst = (float*)pool;                 // [32][132]
#pragma unroll
  for (int mt = 0; mt < 2; ++mt)
#pragma unroll
    for (int r = 0; r < 4; ++r) hst[(mt * 16 + lg * 4 + r) * 132 + cw] = h[mt][r];
  __syncthreads();
  if (tid < BB) {
    float acc = p[pn + OFF_FCB];
    for (int j = 0; j < HH; ++j) acc = fmaf(hst[tid * 132 + j], p[pn + OFF_FCW + j], acc);
    out[n * BATCH + b0 + tid] = sigmoidf_(acc);
  }
}

extern "C" void kernel_launch(void* const* d_in, const int* in_sizes, int n_in,
                              void* d_out, int out_size, void* d_ws, size_t ws_size,
                              hipStream_t stream) {
  const float* p  = (const float*)d_in[0];
  const float* X  = (const float*)d_in[1];
  const float* XL = (const float*)d_in[2];
  const float* XM = (const float*)d_in[3];
  const float* MK = (const float*)d_in[4];
  const float* DE = (const float*)d_in[5];
  float* out = (float*)d_out;
  __bf16* ws = (__bf16*)d_ws;
  if (ws_size < (size_t)WS_ELEMS * 2) return;

  hipLaunchKernelGGL(repack_kernel, dim3(4096), dim3(256), 0, stream, p, ws);
  hipLaunchKernelGGL(grud_main, dim3(NF * (BATCH / BB)), dim3(NTHR), 0, stream,
                     p, X, XL, XM, MK, DE, ws, out);
}

// Round 14
// 242.811 us; speedup vs baseline: 2.6887x; 1.0183x over previous
//
#include <hip/hip_runtime.h>

// GRU-D: nf=64, B=128, T=100, I=64, H=128, C=256.
// R14 = R13 + software-pipelined MFMA placement: x/m-partials of z,r(t+1)
//       computed in D(t); x/m-partial of h_tilde(t) computed in C(t).
//       Critical chains: C = 16 h-MFMA -> sigmoid; D = 8 rh-MFMA -> tanh.
//       tanh via 2*sigmoid(2x)-1.
#define NF 64
#define BATCH 128
#define TT 100
#define II 64
#define HH 128
#define CC 256
#define BB 32
#define NTHR 512
#define PSTRIDE 111297

#define OFF_ZW 0
#define OFF_ZB 32768
#define OFF_RW 32896
#define OFF_RB 65664
#define OFF_HW 65792
#define OFF_HB 98560
#define OFF_GXW 98688
#define OFF_GXB 102784
#define OFF_GHW 102848
#define OFF_GHB 111040
#define OFF_FCW 111168
#define OFF_FCB 111296

// ws layout (bf16 elems), per-lane MFMA B-fragment order (hi only)
#define ZR_PER_N 65536
#define H_BASE   (64 * ZR_PER_N)
#define H_PER_N  32768
#define G_BASE   (H_BASE + 64 * H_PER_N)
#define G_PER_N  8192
#define WS_ELEMS (G_BASE + 64 * G_PER_N)   // 6815744 bf16 = 13 MB

typedef __bf16 bf16x8 __attribute__((ext_vector_type(8)));
typedef __bf16 bf16x4 __attribute__((ext_vector_type(4)));
typedef float f32x4 __attribute__((ext_vector_type(4)));

__device__ __forceinline__ f32x4 mfma16(bf16x8 a, bf16x8 b, f32x4 c) {
  return __builtin_amdgcn_mfma_f32_16x16x32_bf16(a, b, c, 0, 0, 0);
}
__device__ __forceinline__ float rcpf_(float x) { return __builtin_amdgcn_rcpf(x); }
__device__ __forceinline__ float sigmoidf_(float x) { return rcpf_(1.f + __expf(-x)); }
// tanh(x) = 2*sigmoid(2x) - 1
__device__ __forceinline__ float tanhf_(float x) {
  return fmaf(2.f, rcpf_(1.f + __expf(-2.f * x)), -1.f);
}
// row swizzle within a [64][8] plane: physical row = r ^ 2*((r>>4)&3)
__device__ __forceinline__ int SW(int x) { return x ^ (((x >> 4) & 3) << 1); }

// LDS pool element-offsets (plane = [64 rows][8 j] = 512 elems):
#define XA(par, mt, kt)  ((((par)*2 + (mt)) * 2 + (kt)) * 512)
#define MAPL(par, mt, kt) (4096 + XA(par, mt, kt))
#define DAH(mt, kt) (8192 + (((mt)*2 + (kt)) * 512))
#define HAH(mt, q) (10240 + (((mt)*4 + (q)) * 512))
#define RHH(mt, q) (14336 + (((mt)*4 + (q)) * 512))
#define POOL_ELEMS 18432

// ---- repack: params -> B-fragment-ordered bf16 (hi only) in ws ----
__global__ void repack_kernel(const float* __restrict__ p, __bf16* __restrict__ ws) {
  const int total = 4194304 + 2097152 + 524288;
  for (int e = blockIdx.x * 256 + threadIdx.x; e < total; e += gridDim.x * 256) {
    float wv; int dst;
    if (e < 4194304) {  // ZR
      int j = e & 7, l = (e >> 3) & 63, nt = (e >> 9) & 15, kt = (e >> 13) & 7, n = e >> 16;
      int c = kt * 32 + (l >> 4) * 8 + j, l15 = l & 15;
      long pn = (long)n * PSTRIDE;
      wv = (nt < 8) ? p[pn + OFF_ZW + (nt * 16 + l15) * CC + c]
                    : p[pn + OFF_RW + ((nt - 8) * 16 + l15) * CC + c];
      dst = n * ZR_PER_N + (kt * 16 + nt) * 512 + l * 8 + j;
    } else if (e < 4194304 + 2097152) {  // H
      int e2 = e - 4194304;
      int j = e2 & 7, l = (e2 >> 3) & 63, nt = (e2 >> 9) & 7, kt = (e2 >> 12) & 7, n = e2 >> 15;
      int c = kt * 32 + (l >> 4) * 8 + j, l15 = l & 15;
      wv = p[(long)n * PSTRIDE + OFF_HW + (nt * 16 + l15) * CC + c];
      dst = H_BASE + n * H_PER_N + (kt * 8 + nt) * 512 + l * 8 + j;
    } else {  // G
      int e2 = e - (4194304 + 2097152);
      int j = e2 & 7, l = (e2 >> 3) & 63, nt = (e2 >> 9) & 7, kt = (e2 >> 12) & 1, n = e2 >> 13;
      int c = kt * 32 + (l >> 4) * 8 + j, l15 = l & 15;
      wv = p[(long)n * PSTRIDE + OFF_GHW + (nt * 16 + l15) * II + c];
      dst = G_BASE + n * G_PER_N + (kt * 8 + nt) * 512 + l * 8 + j;
    }
    ws[dst] = (__bf16)wv;
  }
}

// One block per (n, 32-batch chunk); 8 waves; 1 block/CU.
__global__ __launch_bounds__(NTHR, 2) void grud_main(
    const float* __restrict__ p, const float* __restrict__ X,
    const float* __restrict__ XL, const float* __restrict__ XM,
    const float* __restrict__ MK, const float* __restrict__ DE,
    const __bf16* __restrict__ ws, float* __restrict__ out) {
  __shared__ __align__(16) __bf16 pool[POOL_ELEMS];

  const int tid = threadIdx.x;
  const int w = tid >> 6, l = tid & 63;
  const int l15 = l & 15, lg = l >> 4;
  const int n = blockIdx.x & 63;            // same-n blocks -> same XCD
  const int b0 = (blockIdx.x >> 6) * BB;
  const long pn = (long)n * PSTRIDE;
  const int cw = w * 16 + l15;
  const int sl = SW(l);

  // ---- all weight fragments in registers (loaded once, 104 VGPR) ----
  bf16x8 wgR[2], wzR[8], wrR[8], whR[8];
  {
    const __bf16* wzr = ws + n * ZR_PER_N;
    const __bf16* wh_ = ws + H_BASE + n * H_PER_N;
    const __bf16* wg_ = ws + G_BASE + n * G_PER_N;
#pragma unroll
    for (int kt = 0; kt < 2; ++kt)
      wgR[kt] = *(const bf16x8*)(wg_ + (kt * 8 + w) * 512 + l * 8);
#pragma unroll
    for (int kt = 0; kt < 8; ++kt) {
      wzR[kt] = *(const bf16x8*)(wzr + (kt * 16 + w) * 512 + l * 8);
      wrR[kt] = *(const bf16x8*)(wzr + (kt * 16 + 8 + w) * 512 + l * 8);
      whR[kt] = *(const bf16x8*)(wh_ + (kt * 8 + w) * 512 + l * 8);
    }
  }

  const float zb = p[pn + OFF_ZB + cw];
  const float rb = p[pn + OFF_RB + cw];
  const float hb = p[pn + OFF_HB + cw];
  const float gb = p[pn + OFF_GHB + cw];
  const f32x4 zb4 = {zb, zb, zb, zb};
  const f32x4 rb4 = {rb, rb, rb, rb};
  const f32x4 hb4 = {hb, hb, hb, hb};
  const f32x4 gb4 = {gb, gb, gb, gb};

  // this lane's h-column coords (global k = 64 + cw)
  const int hq = ((64 + cw) >> 5) - 2;                 // plane q 0..3
  const int qh = (cw >> 3) & 3;
  const int hj = cw & 7;
  int hsrow[4];
#pragma unroll
  for (int r = 0; r < 4; ++r) hsrow[r] = qh * 16 + ((lg * 4 + r) ^ (qh << 1));

  // phase-A mapping: thread -> (batch row 0..31, 4-wide i block)
  const int arow = tid >> 4;
  const int ai0 = (tid & 15) * 4;
  const int amt = arow >> 4;
  const int akt = ai0 >> 5;
  const int salane = SW(((ai0 >> 3) & 3) * 16 + (arow & 15));
  const int aj = ai0 & 7;
  const float* __restrict__ Xp  = X  + (long)(b0 + arow) * TT * II + ai0;
  const float* __restrict__ XLp = XL + (long)(b0 + arow) * TT * II + ai0;
  const float* __restrict__ MKp = MK + ((long)(n * BATCH + b0 + arow) * TT) * II + ai0;
  const float* __restrict__ DEp = DE + ((long)(n * BATCH + b0 + arow) * TT) * II + ai0;
  float gxd4[4], gxb4v[4];
#pragma unroll
  for (int u = 0; u < 4; ++u) {
    gxd4[u] = p[pn + OFF_GXW + (ai0 + u) * 65];
    gxb4v[u] = p[pn + OFF_GXB + ai0 + u];
  }

  float h[2][4] = {{0.f, 0.f, 0.f, 0.f}, {0.f, 0.f, 0.f, 0.f}};
  f32x4 azp[2], arp[2];   // z,r partial accumulators (x/m part of step t)
  f32x4 ahp[2];           // h_tilde partial accumulator (x/m part of step t)

  // ---- prologue: zero hA planes; A(0); prefetch(1) ----
  for (int e = tid; e < 4096; e += NTHR) pool[10240 + e] = (__bf16)0.f;

  f32x4 fx  = *(const f32x4*)Xp;
  f32x4 fxl = *(const f32x4*)XLp;
  f32x4 fxm = *(const f32x4*)(XM + ai0);
  f32x4 fm  = __builtin_nontemporal_load((const f32x4*)MKp);
  f32x4 fd  = __builtin_nontemporal_load((const f32x4*)DEp);
  {
    bf16x4 xh, mh;
#pragma unroll
    for (int u = 0; u < 4; ++u) {
      float m = fm[u], d = fd[u];
      float dx = __expf(-fmaxf(fmaf(d, gxd4[u], gxb4v[u]), 0.f));
      float b = fmaf(dx, fxl[u] - fxm[u], fxm[u]);
      float xv = fmaf(m, fx[u] - b, b);
      xh[u] = (__bf16)xv;
      mh[u] = (__bf16)m;
    }
    *(bf16x4*)&pool[XA(0, amt, akt) + salane * 8 + aj] = xh;
    *(bf16x4*)&pool[MAPL(0, amt, akt) + salane * 8 + aj] = mh;
  }
  {
    const long to = (long)(TT > 1 ? 1 : 0) * II;
    fx  = *(const f32x4*)(Xp + to);
    fxl = *(const f32x4*)(XLp + to);
    fxm = *(const f32x4*)(XM + to + ai0);
    fm  = __builtin_nontemporal_load((const f32x4*)(MKp + to));
    fd  = __builtin_nontemporal_load((const f32x4*)(DEp + to));
  }
  __syncthreads();

  // z,r x/m partials for t=0
#pragma unroll
  for (int mt = 0; mt < 2; ++mt) {
    f32x4 az = zb4, ar = rb4;
#pragma unroll
    for (int kt = 0; kt < 2; ++kt) {
      bf16x8 ah = *(const bf16x8*)&pool[XA(0, mt, kt) + sl * 8];
      az = mfma16(ah, wzR[kt], az);
      ar = mfma16(ah, wrR[kt], ar);
    }
#pragma unroll
    for (int kt = 6; kt < 8; ++kt) {
      bf16x8 ah = *(const bf16x8*)&pool[MAPL(0, mt, kt - 6) + sl * 8];
      az = mfma16(ah, wzR[kt], az);
      ar = mfma16(ah, wrR[kt], ar);
    }
    azp[mt] = az; arp[mt] = ar;
  }

  for (int t = 0; t < TT; ++t) {
    const int par = t & 1, parn = par ^ 1;
    const bool more = (t + 1 < TT);

    // ================= C-region =================
    // A(t+1): elementwise from prefetched regs -> parn planes + dA
    if (more) {
      bf16x4 xh, mh, dh;
#pragma unroll
      for (int u = 0; u < 4; ++u) {
        float m = fm[u], d = fd[u];
        float dx = __expf(-fmaxf(fmaf(d, gxd4[u], gxb4v[u]), 0.f));
        float b = fmaf(dx, fxl[u] - fxm[u], fxm[u]);
        float xv = fmaf(m, fx[u] - b, b);
        xh[u] = (__bf16)xv;
        mh[u] = (__bf16)m;
        dh[u] = (__bf16)d;
      }
      *(bf16x4*)&pool[XA(parn, amt, akt) + salane * 8 + aj] = xh;
      *(bf16x4*)&pool[MAPL(parn, amt, akt) + salane * 8 + aj] = mh;
      *(bf16x4*)&pool[DAH(amt, akt) + salane * 8 + aj] = dh;
      // prefetch t+2
      const long to = (long)(t + 2 < TT ? t + 2 : TT - 1) * II;
      fx  = *(const f32x4*)(Xp + to);
      fxl = *(const f32x4*)(XLp + to);
      fxm = *(const f32x4*)(XM + to + ai0);
      fm  = __builtin_nontemporal_load((const f32x4*)(MKp + to));
      fd  = __builtin_nontemporal_load((const f32x4*)(DEp + to));
    }

    // z,r: finish with h-part (critical); also start h_tilde x/m partial
    float zv[2][4];
#pragma unroll
    for (int mt = 0; mt < 2; ++mt) {
      f32x4 az = azp[mt], ar = arp[mt];
#pragma unroll
      for (int kt = 2; kt < 6; ++kt) {
        bf16x8 ah = *(const bf16x8*)&pool[HAH(mt, kt - 2) + sl * 8];
        az = mfma16(ah, wzR[kt], az);
        ar = mfma16(ah, wrR[kt], ar);
      }
      // h_tilde x/m partial (off critical path)
      f32x4 ahh = hb4;
#pragma unroll
      for (int kt = 0; kt < 2; ++kt) {
        bf16x8 ah = *(const bf16x8*)&pool[XA(par, mt, kt) + sl * 8];
        ahh = mfma16(ah, whR[kt], ahh);
      }
#pragma unroll
      for (int kt = 6; kt < 8; ++kt) {
        bf16x8 ah = *(const bf16x8*)&pool[MAPL(par, mt, kt - 6) + sl * 8];
        ahh = mfma16(ah, whR[kt], ahh);
      }
      ahp[mt] = ahh;
#pragma unroll
      for (int r = 0; r < 4; ++r) {
        zv[mt][r] = sigmoidf_(az[r]);
        float rv = sigmoidf_(ar[r]);
        float rh = rv * h[mt][r];
        pool[RHH(mt, hq) + hsrow[r] * 8 + hj] = (__bf16)rh;
      }
    }
    __syncthreads();  // bar1

    // ================= D-region =================
#pragma unroll
    for (int mt = 0; mt < 2; ++mt) {
      // finish h_tilde with rh-part (critical)
      f32x4 ahh = ahp[mt];
#pragma unroll
      for (int kt = 2; kt < 6; ++kt) {
        bf16x8 ah = *(const bf16x8*)&pool[RHH(mt, kt - 2) + sl * 8];
        ahh = mfma16(ah, whR[kt], ahh);
      }
      // delta_h(t+1) + next-step z,r x/m partials (off critical path)
      f32x4 ad = gb4;
      if (more) {
#pragma unroll
        for (int kt = 0; kt < 2; ++kt) {
          bf16x8 ah = *(const bf16x8*)&pool[DAH(mt, kt) + sl * 8];
          ad = mfma16(ah, wgR[kt], ad);
        }
        f32x4 az = zb4, ar = rb4;
#pragma unroll
        for (int kt = 0; kt < 2; ++kt) {
          bf16x8 ah = *(const bf16x8*)&pool[XA(parn, mt, kt) + sl * 8];
          az = mfma16(ah, wzR[kt], az);
          ar = mfma16(ah, wrR[kt], ar);
        }
#pragma unroll
        for (int kt = 6; kt < 8; ++kt) {
          bf16x8 ah = *(const bf16x8*)&pool[MAPL(parn, mt, kt - 6) + sl * 8];
          az = mfma16(ah, wzR[kt], az);
          ar = mfma16(ah, wrR[kt], ar);
        }
        azp[mt] = az; arp[mt] = ar;
      }
#pragma unroll
      for (int r = 0; r < 4; ++r) {
        float ht = tanhf_(ahh[r]);
        float hn = fmaf(zv[mt][r], ht - h[mt][r], h[mt][r]);
        if (more) {
          hn *= __expf(-fmaxf(ad[r], 0.f));        // decay for step t+1
          pool[HAH(mt, hq) + hsrow[r] * 8 + hj] = (__bf16)hn;
        }
        h[mt][r] = hn;
      }
    }
    __syncthreads();  // bar2
  }

  // ---- fc epilogue (overlays pool) ----
  float* hst = (float*)pool;                 // [32][132]
#pragma unroll
  for (int mt = 0; mt < 2; ++mt)
#pragma unroll
    for (int r = 0; r < 4; ++r) hst[(mt * 16 + lg * 4 + r) * 132 + cw] = h[mt][r];
  __syncthreads();
  if (tid < BB) {
    float acc = p[pn + OFF_FCB];
    for (int j = 0; j < HH; ++j) acc = fmaf(hst[tid * 132 + j], p[pn + OFF_FCW + j], acc);
    out[n * BATCH + b0 + tid] = sigmoidf_(acc);
  }
}

extern "C" void kernel_launch(void* const* d_in, const int* in_sizes, int n_in,
                              void* d_out, int out_size, void* d_ws, size_t ws_size,
                              hipStream_t stream) {
  const float* p  = (const float*)d_in[0];
  const float* X  = (const float*)d_in[1];
  const float* XL = (const float*)d_in[2];
  const float* XM = (const float*)d_in[3];
  const float* MK = (const float*)d_in[4];
  const float* DE = (const float*)d_in[5];
  float* out = (float*)d_out;
  __bf16* ws = (__bf16*)d_ws;
  if (ws_size < (size_t)WS_ELEMS * 2) return;

  hipLaunchKernelGGL(repack_kernel, dim3(4096), dim3(256), 0, stream, p, ws);
  hipLaunchKernelGGL(grud_main, dim3(NF * (BATCH / BB)), dim3(NTHR), 0, stream,
                     p, X, XL, XM, MK, DE, ws, out);
}

// Round 15
// 225.758 us; speedup vs baseline: 2.8918x; 1.0755x over previous
//
#include <hip/hip_runtime.h>

// GRU-D: nf=64, B=128, T=100, I=64, H=128, C=256.
// R15 = R14 + exp2-folding (weights/biases pre-scaled by log2e; h-weights by
//       2*log2e for tanh=2*sig(2x)-1) + z-sigmoid moved across bar1 into D.
#define NF 64
#define BATCH 128
#define TT 100
#define II 64
#define HH 128
#define CC 256
#define BB 32
#define NTHR 512
#define PSTRIDE 111297

#define OFF_ZW 0
#define OFF_ZB 32768
#define OFF_RW 32896
#define OFF_RB 65664
#define OFF_HW 65792
#define OFF_HB 98560
#define OFF_GXW 98688
#define OFF_GXB 102784
#define OFF_GHW 102848
#define OFF_GHB 111040
#define OFF_FCW 111168
#define OFF_FCB 111296

#define LOG2E 1.4426950408889634f

// ws layout (bf16 elems), per-lane MFMA B-fragment order (hi only, pre-scaled)
#define ZR_PER_N 65536
#define H_BASE   (64 * ZR_PER_N)
#define H_PER_N  32768
#define G_BASE   (H_BASE + 64 * H_PER_N)
#define G_PER_N  8192
#define WS_ELEMS (G_BASE + 64 * G_PER_N)   // 6815744 bf16 = 13 MB

typedef __bf16 bf16x8 __attribute__((ext_vector_type(8)));
typedef __bf16 bf16x4 __attribute__((ext_vector_type(4)));
typedef float f32x4 __attribute__((ext_vector_type(4)));

__device__ __forceinline__ f32x4 mfma16(bf16x8 a, bf16x8 b, f32x4 c) {
  return __builtin_amdgcn_mfma_f32_16x16x32_bf16(a, b, c, 0, 0, 0);
}
__device__ __forceinline__ float rcpf_(float x) { return __builtin_amdgcn_rcpf(x); }
__device__ __forceinline__ float exp2_(float x) { return __builtin_amdgcn_exp2f(x); }
// inputs already scaled by log2e:
__device__ __forceinline__ float sig2_(float x) { return rcpf_(1.f + exp2_(-x)); }
// input already scaled by 2*log2e:
__device__ __forceinline__ float tanh2_(float x) {
  return fmaf(2.f, rcpf_(1.f + exp2_(-x)), -1.f);
}
// row swizzle within a [64][8] plane: physical row = r ^ 2*((r>>4)&3)
__device__ __forceinline__ int SW(int x) { return x ^ (((x >> 4) & 3) << 1); }

// LDS pool element-offsets (plane = [64 rows][8 j] = 512 elems):
#define XA(par, mt, kt)  ((((par)*2 + (mt)) * 2 + (kt)) * 512)
#define MAPL(par, mt, kt) (4096 + XA(par, mt, kt))
#define DAH(mt, kt) (8192 + (((mt)*2 + (kt)) * 512))
#define HAH(mt, q) (10240 + (((mt)*4 + (q)) * 512))
#define RHH(mt, q) (14336 + (((mt)*4 + (q)) * 512))
#define POOL_ELEMS 18432

// ---- repack: params -> B-fragment-ordered bf16 (hi only, log2e-scaled) ----
__global__ void repack_kernel(const float* __restrict__ p, __bf16* __restrict__ ws) {
  const int total = 4194304 + 2097152 + 524288;
  for (int e = blockIdx.x * 256 + threadIdx.x; e < total; e += gridDim.x * 256) {
    float wv; int dst;
    if (e < 4194304) {  // ZR  (scale log2e)
      int j = e & 7, l = (e >> 3) & 63, nt = (e >> 9) & 15, kt = (e >> 13) & 7, n = e >> 16;
      int c = kt * 32 + (l >> 4) * 8 + j, l15 = l & 15;
      long pn = (long)n * PSTRIDE;
      wv = (nt < 8) ? p[pn + OFF_ZW + (nt * 16 + l15) * CC + c]
                    : p[pn + OFF_RW + ((nt - 8) * 16 + l15) * CC + c];
      wv *= LOG2E;
      dst = n * ZR_PER_N + (kt * 16 + nt) * 512 + l * 8 + j;
    } else if (e < 4194304 + 2097152) {  // H  (scale 2*log2e for tanh form)
      int e2 = e - 4194304;
      int j = e2 & 7, l = (e2 >> 3) & 63, nt = (e2 >> 9) & 7, kt = (e2 >> 12) & 7, n = e2 >> 15;
      int c = kt * 32 + (l >> 4) * 8 + j, l15 = l & 15;
      wv = p[(long)n * PSTRIDE + OFF_HW + (nt * 16 + l15) * CC + c] * (2.f * LOG2E);
      dst = H_BASE + n * H_PER_N + (kt * 8 + nt) * 512 + l * 8 + j;
    } else {  // G  (scale log2e)
      int e2 = e - (4194304 + 2097152);
      int j = e2 & 7, l = (e2 >> 3) & 63, nt = (e2 >> 9) & 7, kt = (e2 >> 12) & 1, n = e2 >> 13;
      int c = kt * 32 + (l >> 4) * 8 + j, l15 = l & 15;
      wv = p[(long)n * PSTRIDE + OFF_GHW + (nt * 16 + l15) * II + c] * LOG2E;
      dst = G_BASE + n * G_PER_N + (kt * 8 + nt) * 512 + l * 8 + j;
    }
    ws[dst] = (__bf16)wv;
  }
}

// One block per (n, 32-batch chunk); 8 waves; 1 block/CU.
__global__ __launch_bounds__(NTHR, 2) void grud_main(
    const float* __restrict__ p, const float* __restrict__ X,
    const float* __restrict__ XL, const float* __restrict__ XM,
    const float* __restrict__ MK, const float* __restrict__ DE,
    const __bf16* __restrict__ ws, float* __restrict__ out) {
  __shared__ __align__(16) __bf16 pool[POOL_ELEMS];

  const int tid = threadIdx.x;
  const int w = tid >> 6, l = tid & 63;
  const int l15 = l & 15, lg = l >> 4;
  const int n = blockIdx.x & 63;            // same-n blocks -> same XCD
  const int b0 = (blockIdx.x >> 6) * BB;
  const long pn = (long)n * PSTRIDE;
  const int cw = w * 16 + l15;
  const int sl = SW(l);

  // ---- all weight fragments in registers (loaded once, 104 VGPR) ----
  bf16x8 wgR[2], wzR[8], wrR[8], whR[8];
  {
    const __bf16* wzr = ws + n * ZR_PER_N;
    const __bf16* wh_ = ws + H_BASE + n * H_PER_N;
    const __bf16* wg_ = ws + G_BASE + n * G_PER_N;
#pragma unroll
    for (int kt = 0; kt < 2; ++kt)
      wgR[kt] = *(const bf16x8*)(wg_ + (kt * 8 + w) * 512 + l * 8);
#pragma unroll
    for (int kt = 0; kt < 8; ++kt) {
      wzR[kt] = *(const bf16x8*)(wzr + (kt * 16 + w) * 512 + l * 8);
      wrR[kt] = *(const bf16x8*)(wzr + (kt * 16 + 8 + w) * 512 + l * 8);
      whR[kt] = *(const bf16x8*)(wh_ + (kt * 8 + w) * 512 + l * 8);
    }
  }

  const float zb = p[pn + OFF_ZB + cw] * LOG2E;
  const float rb = p[pn + OFF_RB + cw] * LOG2E;
  const float hb = p[pn + OFF_HB + cw] * (2.f * LOG2E);
  const float gb = p[pn + OFF_GHB + cw] * LOG2E;
  const f32x4 zb4 = {zb, zb, zb, zb};
  const f32x4 rb4 = {rb, rb, rb, rb};
  const f32x4 hb4 = {hb, hb, hb, hb};
  const f32x4 gb4 = {gb, gb, gb, gb};

  // this lane's h-column coords (global k = 64 + cw)
  const int hq = ((64 + cw) >> 5) - 2;                 // plane q 0..3
  const int qh = (cw >> 3) & 3;
  const int hj = cw & 7;
  int hsrow[4];
#pragma unroll
  for (int r = 0; r < 4; ++r) hsrow[r] = qh * 16 + ((lg * 4 + r) ^ (qh << 1));

  // phase-A mapping: thread -> (batch row 0..31, 4-wide i block)
  const int arow = tid >> 4;
  const int ai0 = (tid & 15) * 4;
  const int amt = arow >> 4;
  const int akt = ai0 >> 5;
  const int salane = SW(((ai0 >> 3) & 3) * 16 + (arow & 15));
  const int aj = ai0 & 7;
  const float* __restrict__ Xp  = X  + (long)(b0 + arow) * TT * II + ai0;
  const float* __restrict__ XLp = XL + (long)(b0 + arow) * TT * II + ai0;
  const float* __restrict__ MKp = MK + ((long)(n * BATCH + b0 + arow) * TT) * II + ai0;
  const float* __restrict__ DEp = DE + ((long)(n * BATCH + b0 + arow) * TT) * II + ai0;
  float gxd4[4], gxb4v[4];
#pragma unroll
  for (int u = 0; u < 4; ++u) {
    gxd4[u] = p[pn + OFF_GXW + (ai0 + u) * 65] * LOG2E;
    gxb4v[u] = p[pn + OFF_GXB + ai0 + u] * LOG2E;
  }

  float h[2][4] = {{0.f, 0.f, 0.f, 0.f}, {0.f, 0.f, 0.f, 0.f}};
  f32x4 azp[2], arp[2];   // z,r partial accumulators (x/m part of step t)
  f32x4 ahp[2];           // h_tilde partial accumulator (x/m part of step t)
  f32x4 azs[2];           // completed z pre-activations, consumed in D

  // ---- prologue: zero hA planes; A(0); prefetch(1) ----
  for (int e = tid; e < 4096; e += NTHR) pool[10240 + e] = (__bf16)0.f;

  f32x4 fx  = *(const f32x4*)Xp;
  f32x4 fxl = *(const f32x4*)XLp;
  f32x4 fxm = *(const f32x4*)(XM + ai0);
  f32x4 fm  = __builtin_nontemporal_load((const f32x4*)MKp);
  f32x4 fd  = __builtin_nontemporal_load((const f32x4*)DEp);
  {
    bf16x4 xh, mh;
#pragma unroll
    for (int u = 0; u < 4; ++u) {
      float m = fm[u], d = fd[u];
      float dx = exp2_(-fmaxf(fmaf(d, gxd4[u], gxb4v[u]), 0.f));
      float b = fmaf(dx, fxl[u] - fxm[u], fxm[u]);
      float xv = fmaf(m, fx[u] - b, b);
      xh[u] = (__bf16)xv;
      mh[u] = (__bf16)m;
    }
    *(bf16x4*)&pool[XA(0, amt, akt) + salane * 8 + aj] = xh;
    *(bf16x4*)&pool[MAPL(0, amt, akt) + salane * 8 + aj] = mh;
  }
  {
    const long to = (long)(TT > 1 ? 1 : 0) * II;
    fx  = *(const f32x4*)(Xp + to);
    fxl = *(const f32x4*)(XLp + to);
    fxm = *(const f32x4*)(XM + to + ai0);
    fm  = __builtin_nontemporal_load((const f32x4*)(MKp + to));
    fd  = __builtin_nontemporal_load((const f32x4*)(DEp + to));
  }
  __syncthreads();

  // z,r x/m partials for t=0
#pragma unroll
  for (int mt = 0; mt < 2; ++mt) {
    f32x4 az = zb4, ar = rb4;
#pragma unroll
    for (int kt = 0; kt < 2; ++kt) {
      bf16x8 ah = *(const bf16x8*)&pool[XA(0, mt, kt) + sl * 8];
      az = mfma16(ah, wzR[kt], az);
      ar = mfma16(ah, wrR[kt], ar);
    }
#pragma unroll
    for (int kt = 6; kt < 8; ++kt) {
      bf16x8 ah = *(const bf16x8*)&pool[MAPL(0, mt, kt - 6) + sl * 8];
      az = mfma16(ah, wzR[kt], az);
      ar = mfma16(ah, wrR[kt], ar);
    }
    azp[mt] = az; arp[mt] = ar;
  }

  for (int t = 0; t < TT; ++t) {
    const int par = t & 1, parn = par ^ 1;
    const bool more = (t + 1 < TT);

    // ================= C-region =================
    // A(t+1): elementwise from prefetched regs -> parn planes + dA
    if (more) {
      bf16x4 xh, mh, dh;
#pragma unroll
      for (int u = 0; u < 4; ++u) {
        float m = fm[u], d = fd[u];
        float dx = exp2_(-fmaxf(fmaf(d, gxd4[u], gxb4v[u]), 0.f));
        float b = fmaf(dx, fxl[u] - fxm[u], fxm[u]);
        float xv = fmaf(m, fx[u] - b, b);
        xh[u] = (__bf16)xv;
        mh[u] = (__bf16)m;
        dh[u] = (__bf16)d;
      }
      *(bf16x4*)&pool[XA(parn, amt, akt) + salane * 8 + aj] = xh;
      *(bf16x4*)&pool[MAPL(parn, amt, akt) + salane * 8 + aj] = mh;
      *(bf16x4*)&pool[DAH(amt, akt) + salane * 8 + aj] = dh;
      // prefetch t+2
      const long to = (long)(t + 2 < TT ? t + 2 : TT - 1) * II;
      fx  = *(const f32x4*)(Xp + to);
      fxl = *(const f32x4*)(XLp + to);
      fxm = *(const f32x4*)(XM + to + ai0);
      fm  = __builtin_nontemporal_load((const f32x4*)(MKp + to));
      fd  = __builtin_nontemporal_load((const f32x4*)(DEp + to));
    }

    // z,r: finish with h-part; r-sigmoid + rh-store (critical); z deferred to D
#pragma unroll
    for (int mt = 0; mt < 2; ++mt) {
      f32x4 az = azp[mt], ar = arp[mt];
#pragma unroll
      for (int kt = 2; kt < 6; ++kt) {
        bf16x8 ah = *(const bf16x8*)&pool[HAH(mt, kt - 2) + sl * 8];
        az = mfma16(ah, wzR[kt], az);
        ar = mfma16(ah, wrR[kt], ar);
      }
      azs[mt] = az;                          // z pre-act; sigmoid in D
      // h_tilde x/m partial (off critical path)
      f32x4 ahh = hb4;
#pragma unroll
      for (int kt = 0; kt < 2; ++kt) {
        bf16x8 ah = *(const bf16x8*)&pool[XA(par, mt, kt) + sl * 8];
        ahh = mfma16(ah, whR[kt], ahh);
      }
#pragma unroll
      for (int kt = 6; kt < 8; ++kt) {
        bf16x8 ah = *(const bf16x8*)&pool[MAPL(par, mt, kt - 6) + sl * 8];
        ahh = mfma16(ah, whR[kt], ahh);
      }
      ahp[mt] = ahh;
#pragma unroll
      for (int r = 0; r < 4; ++r) {
        float rv = sig2_(ar[r]);
        float rh = rv * h[mt][r];
        pool[RHH(mt, hq) + hsrow[r] * 8 + hj] = (__bf16)rh;
      }
    }
    __syncthreads();  // bar1

    // ================= D-region =================
#pragma unroll
    for (int mt = 0; mt < 2; ++mt) {
      // finish h_tilde with rh-part (critical)
      f32x4 ahh = ahp[mt];
#pragma unroll
      for (int kt = 2; kt < 6; ++kt) {
        bf16x8 ah = *(const bf16x8*)&pool[RHH(mt, kt - 2) + sl * 8];
        ahh = mfma16(ah, whR[kt], ahh);
      }
      // z-sigmoid (deferred from C; hides under MFMAs)
      float zv[4];
#pragma unroll
      for (int r = 0; r < 4; ++r) zv[r] = sig2_(azs[mt][r]);
      // delta_h(t+1) + next-step z,r x/m partials (off critical path)
      f32x4 ad = gb4;
      if (more) {
#pragma unroll
        for (int kt = 0; kt < 2; ++kt) {
          bf16x8 ah = *(const bf16x8*)&pool[DAH(mt, kt) + sl * 8];
          ad = mfma16(ah, wgR[kt], ad);
        }
        f32x4 az = zb4, ar = rb4;
#pragma unroll
        for (int kt = 0; kt < 2; ++kt) {
          bf16x8 ah = *(const bf16x8*)&pool[XA(parn, mt, kt) + sl * 8];
          az = mfma16(ah, wzR[kt], az);
          ar = mfma16(ah, wrR[kt], ar);
        }
#pragma unroll
        for (int kt = 6; kt < 8; ++kt) {
          bf16x8 ah = *(const bf16x8*)&pool[MAPL(parn, mt, kt - 6) + sl * 8];
          az = mfma16(ah, wzR[kt], az);
          ar = mfma16(ah, wrR[kt], ar);
        }
        azp[mt] = az; arp[mt] = ar;
      }
#pragma unroll
      for (int r = 0; r < 4; ++r) {
        float ht = tanh2_(ahh[r]);
        float hn = fmaf(zv[r], ht - h[mt][r], h[mt][r]);
        if (more) {
          hn *= exp2_(-fmaxf(ad[r], 0.f));         // decay for step t+1
          pool[HAH(mt, hq) + hsrow[r] * 8 + hj] = (__bf16)hn;
        }
        h[mt][r] = hn;
      }
    }
    __syncthreads();  // bar2
  }

  // ---- fc epilogue (overlays pool) ----
  float* hst = (float*)pool;                 // [32][132]
#pragma unroll
  for (int mt = 0; mt < 2; ++mt)
#pragma unroll
    for (int r = 0; r < 4; ++r) hst[(mt * 16 + lg * 4 + r) * 132 + cw] = h[mt][r];
  __syncthreads();
  if (tid < BB) {
    float acc = p[pn + OFF_FCB];
    for (int j = 0; j < HH; ++j) acc = fmaf(hst[tid * 132 + j], p[pn + OFF_FCW + j], acc);
    out[n * BATCH + b0 + tid] = rcpf_(1.f + exp2_(-acc * LOG2E));
  }
}

extern "C" void kernel_launch(void* const* d_in, const int* in_sizes, int n_in,
                              void* d_out, int out_size, void* d_ws, size_t ws_size,
                              hipStream_t stream) {
  const float* p  = (const float*)d_in[0];
  const float* X  = (const float*)d_in[1];
  const float* XL = (const float*)d_in[2];
  const float* XM = (const float*)d_in[3];
  const float* MK = (const float*)d_in[4];
  const float* DE = (const float*)d_in[5];
  float* out = (float*)d_out;
  __bf16* ws = (__bf16*)d_ws;
  if (ws_size < (size_t)WS_ELEMS * 2) return;

  hipLaunchKernelGGL(repack_kernel, dim3(4096), dim3(256), 0, stream, p, ws);
  hipLaunchKernelGGL(grud_main, dim3(NF * (BATCH / BB)), dim3(NTHR), 0, stream,
                     p, X, XL, XM, MK, DE, ws, out);
}